// Round 1
// baseline (595.062 us; speedup 1.0000x reference)
//
#include <hip/hip_runtime.h>
#include <math.h>

#define BNTOT 8192      // B*N
#define CH    64        // channels
#define KP1   11        // K+1 neighbors
#define NLOC  1568      // B * E  (8 * 196)

// ---------- helpers ----------
// number of even patch origins i in [max(0,p-4), min(26,p)]
__device__ __forceinline__ int pcnt(int p) {
  int lo = p - 4; if (lo < 0) lo = 0; lo += (lo & 1);
  int hi = p; if (hi > 26) hi = 26;
  return (hi >= lo) ? (((hi - lo) >> 1) + 1) : 0;
}
// Dv^{-1/2} for node u : Dv = 11 (KNN memberships) + local patch count (static)
__device__ __forceinline__ float dv2_of(int u) {
  int node = u & 1023;
  int rr = node >> 5, cc = node & 31;
  int dv = KP1 + pcnt(rr) * pcnt(cc);
  return 1.0f / sqrtf((float)dv);
}

// ---------- K0: row squared norms ----------
__global__ void k_sq(const float* __restrict__ X, float* __restrict__ sq) {
  int row  = (blockIdx.x * blockDim.x + threadIdx.x) >> 6;
  int lane = threadIdx.x & 63;
  float v = X[row * CH + lane];
  v *= v;
  #pragma unroll
  for (int off = 32; off >= 1; off >>= 1) v += __shfl_xor(v, off, 64);
  if (lane == 0) sq[row] = v;
}

// ---------- K1: fused distance + per-lane top-11 ----------
// grid 256: blockIdx = rg*2 + h  (rg = 64-row group, h = column half)
// block 512 = 8 waves; lane owns row rg*64+lane; wave w scans cols
// [h*4096 + w*512, +512). Column data via wave-uniform scalar loads.
__global__ __launch_bounds__(512, 2)
void k_topk(const float* __restrict__ X, const float* __restrict__ sq,
            float* __restrict__ candv, int* __restrict__ candi) {
  const int tid  = threadIdx.x;
  const int wave = tid >> 6;
  const int lane = tid & 63;
  const int rg   = blockIdx.x >> 1;
  const int h    = blockIdx.x & 1;
  const int row  = rg * 64 + lane;
  const int colbase = h * 4096 + wave * 512;

  // own row into registers (64 VGPRs)
  float xr[CH];
  {
    const float4* xp = (const float4*)(X + (size_t)row * CH);
    #pragma unroll
    for (int k = 0; k < CH / 4; ++k) {
      float4 v = xp[k];
      xr[4*k+0] = v.x; xr[4*k+1] = v.y; xr[4*k+2] = v.z; xr[4*k+3] = v.w;
    }
  }

  float tv[KP1]; int ti[KP1];
  #pragma unroll
  for (int t = 0; t < KP1; ++t) { tv[t] = INFINITY; ti[t] = -1; }

  for (int n = 0; n < 512; ++n) {
    int j = __builtin_amdgcn_readfirstlane(colbase + n);   // wave-uniform
    const float* cp = X + (size_t)j * CH;                  // -> s_load
    float d0 = 0.f, d1 = 0.f, d2 = 0.f, d3 = 0.f;
    #pragma unroll
    for (int k = 0; k < CH / 4; ++k) {
      d0 = fmaf(xr[4*k+0], cp[4*k+0], d0);
      d1 = fmaf(xr[4*k+1], cp[4*k+1], d1);
      d2 = fmaf(xr[4*k+2], cp[4*k+2], d2);
      d3 = fmaf(xr[4*k+3], cp[4*k+3], d3);
    }
    // ordering-equivalent score: sq_j - 2*dot (sq_i is a per-row constant)
    float score = fmaf(-2.0f, (d0 + d1) + (d2 + d3), sq[j]);
    if (score < tv[KP1 - 1]) {
      float cv = score; int ci = j;
      #pragma unroll
      for (int t = 0; t < KP1; ++t) {
        bool sw = cv < tv[t];
        float nv = sw ? cv   : tv[t]; int ni = sw ? ci   : ti[t];
        float ov = sw ? tv[t] : cv;   int oi = sw ? ti[t] : ci;
        tv[t] = nv; ti[t] = ni; cv = ov; ci = oi;
      }
    }
  }

  // merge the 8 waves' lists (same 64 rows in every wave) through LDS
  __shared__ float mv[8][64][KP1];
  __shared__ int   mi[8][64][KP1];
  #pragma unroll
  for (int t = 0; t < KP1; ++t) { mv[wave][lane][t] = tv[t]; mi[wave][lane][t] = ti[t]; }
  __syncthreads();
  if (tid < 64) {
    const int r = tid;
    float v[KP1]; int id[KP1];
    #pragma unroll
    for (int t = 0; t < KP1; ++t) { v[t] = mv[0][r][t]; id[t] = mi[0][r][t]; }
    for (int w = 1; w < 8; ++w) {
      #pragma unroll
      for (int t = 0; t < KP1; ++t) {
        float cv = mv[w][r][t]; int ci = mi[w][r][t];
        if (cv < v[KP1 - 1]) {
          #pragma unroll
          for (int s = 0; s < KP1; ++s) {
            bool sw = cv < v[s];
            float nv = sw ? cv   : v[s]; int ni = sw ? ci   : id[s];
            float ov = sw ? v[s] : cv;   int oi = sw ? id[s] : ci;
            v[s] = nv; id[s] = ni; cv = ov; ci = oi;
          }
        }
      }
    }
    size_t base = ((size_t)blockIdx.x * 64 + r) * KP1;
    #pragma unroll
    for (int t = 0; t < KP1; ++t) { candv[base + t] = v[t]; candi[base + t] = id[t]; }
  }
}

// ---------- K1b: merge the two column-half candidate lists ----------
__global__ void k_topk_merge(const float* __restrict__ candv, const int* __restrict__ candi,
                             int* __restrict__ inds, int* __restrict__ DE) {
  int row = blockIdx.x * 256 + threadIdx.x;        // 0..8191
  int rg = row >> 6, l = row & 63;
  size_t o0 = ((size_t)(rg * 2)     * 64 + l) * KP1;
  size_t o1 = ((size_t)(rg * 2 + 1) * 64 + l) * KP1;
  float v[KP1]; int id[KP1];
  #pragma unroll
  for (int t = 0; t < KP1; ++t) { v[t] = candv[o0 + t]; id[t] = candi[o0 + t]; }
  #pragma unroll
  for (int t = 0; t < KP1; ++t) {
    float cv = candv[o1 + t]; int ci = candi[o1 + t];
    if (cv < v[KP1 - 1]) {
      #pragma unroll
      for (int s = 0; s < KP1; ++s) {
        bool sw = cv < v[s];
        float nv = sw ? cv   : v[s]; int ni = sw ? ci   : id[s];
        float ov = sw ? v[s] : cv;   int oi = sw ? id[s] : ci;
        v[s] = nv; id[s] = ni; cv = ov; ci = oi;
      }
    }
  }
  #pragma unroll
  for (int t = 0; t < KP1; ++t) {
    inds[row * KP1 + t] = id[t];
    atomicAdd(&DE[id[t]], 1);
  }
}

// ---------- K3: t = Dv^{-1/2} * (x @ W^T + b) ----------
// wave: lane c holds W row c in regs; iterates 16 rows with scalar x loads.
__global__ void k_lin(const float* __restrict__ X, const float* __restrict__ W,
                      const float* __restrict__ bias, float* __restrict__ t) {
  int lane = threadIdx.x & 63;
  int wave = threadIdx.x >> 6;
  int rowbase = (blockIdx.x * 4 + wave) * 16;
  float wr[CH];
  {
    const float4* wp = (const float4*)(W + (size_t)lane * CH);
    #pragma unroll
    for (int k = 0; k < CH / 4; ++k) {
      float4 v = wp[k];
      wr[4*k+0] = v.x; wr[4*k+1] = v.y; wr[4*k+2] = v.z; wr[4*k+3] = v.w;
    }
  }
  float bc = bias[lane];
  for (int r = 0; r < 16; ++r) {
    int row = __builtin_amdgcn_readfirstlane(rowbase + r);
    const float* xp = X + (size_t)row * CH;   // wave-uniform -> s_load
    float d0 = 0.f, d1 = 0.f, d2 = 0.f, d3 = 0.f;
    #pragma unroll
    for (int k = 0; k < CH / 4; ++k) {
      d0 = fmaf(wr[4*k+0], xp[4*k+0], d0);
      d1 = fmaf(wr[4*k+1], xp[4*k+1], d1);
      d2 = fmaf(wr[4*k+2], xp[4*k+2], d2);
      d3 = fmaf(wr[4*k+3], xp[4*k+3], d3);
    }
    float y = (d0 + d1) + (d2 + d3) + bc;
    t[(size_t)row * CH + lane] = y * dv2_of(row);
  }
}

// ---------- K4a: scatter t into KNN edge sums (s_knn[e] += t[u], e in inds[u]) ----------
__global__ void k_scatter(const float* __restrict__ t, const int* __restrict__ inds,
                          float* __restrict__ s_knn) {
  int c = threadIdx.x & 63;
  int u = blockIdx.x * 4 + (threadIdx.x >> 6);
  float val = t[(size_t)u * CH + c];
  int ub = __builtin_amdgcn_readfirstlane(u);
  const int* ip = inds + (size_t)ub * KP1;
  #pragma unroll
  for (int j = 0; j < KP1; ++j) {
    int e = ip[j];
    atomicAdd(&s_knn[(size_t)e * CH + c], val);
  }
}

// ---------- K4b: local patch edge sums, pre-scaled by 1/De (=1/25) ----------
__global__ void k_local(const float* __restrict__ t, float* __restrict__ s_loc) {
  int c = threadIdx.x & 63;
  int e = blockIdx.x * 4 + (threadIdx.x >> 6);
  int b  = e / 196;
  int le = e - b * 196;
  int pi = le / 14;
  int pj = le - pi * 14;
  int base = b * 1024 + (pi * 2) * 32 + pj * 2;
  float acc = 0.f;
  #pragma unroll
  for (int di = 0; di < 5; ++di)
    #pragma unroll
    for (int dj = 0; dj < 5; ++dj)
      acc += t[(size_t)(base + di * 32 + dj) * CH + c];
  s_loc[(size_t)e * CH + c] = acc * (1.0f / 25.0f);
}

// ---------- K5: z[u] = dv2_u * ( sum_knn s_knn[e]/DE[e] + sum_local s_loc[p] ) ----------
__global__ void k_gather(const float* __restrict__ s_knn, const float* __restrict__ s_loc,
                         const int* __restrict__ inds, const int* __restrict__ DE,
                         float* __restrict__ z) {
  int c = threadIdx.x & 63;
  int u = blockIdx.x * 4 + (threadIdx.x >> 6);
  int ub = __builtin_amdgcn_readfirstlane(u);
  const int* ip = inds + (size_t)ub * KP1;
  float acc = 0.f;
  #pragma unroll
  for (int j = 0; j < KP1; ++j) {
    int e = ip[j];
    float invde = 1.0f / (float)DE[e];
    acc += s_knn[(size_t)e * CH + c] * invde;
  }
  int node = ub & 1023, b = ub >> 10;
  int rr = node >> 5, cc = node & 31;
  int i0 = rr - 4; if (i0 < 0) i0 = 0; i0 += (i0 & 1);
  int i1 = rr; if (i1 > 26) i1 = 26;
  int j0 = cc - 4; if (j0 < 0) j0 = 0; j0 += (j0 & 1);
  int j1 = cc; if (j1 > 26) j1 = 26;
  for (int i = i0; i <= i1; i += 2)
    for (int jj = j0; jj <= j1; jj += 2) {
      int e = b * 196 + (i >> 1) * 14 + (jj >> 1);
      acc += s_loc[(size_t)e * CH + c];
    }
  z[(size_t)ub * CH + c] = acc * dv2_of(ub);
}

// ---------- K6a: per-64-row-block partial BN sums ----------
__global__ void k_bnpart(const float* __restrict__ z, float* __restrict__ part,
                         float* __restrict__ partsq) {
  int c = threadIdx.x & 63;
  int rq = threadIdx.x >> 6;
  int blk = blockIdx.x;
  float s = 0.f, s2 = 0.f;
  for (int k = 0; k < 16; ++k) {
    float v = z[(size_t)(blk * 64 + rq * 16 + k) * CH + c];
    s += v; s2 += v * v;
  }
  __shared__ float ls[4][CH], ls2[4][CH];
  ls[rq][c] = s; ls2[rq][c] = s2;
  __syncthreads();
  if (rq == 0) {
    part[(size_t)blk * CH + c]   = ls[0][c] + ls[1][c] + ls[2][c] + ls[3][c];
    partsq[(size_t)blk * CH + c] = ls2[0][c] + ls2[1][c] + ls2[2][c] + ls2[3][c];
  }
}

// ---------- K6b: finalize mu / rstd ----------
__global__ void k_bnfin(const float* __restrict__ part, const float* __restrict__ partsq,
                        float* __restrict__ mu, float* __restrict__ rstd) {
  int c = threadIdx.x;
  float s = 0.f, s2 = 0.f;
  for (int b = 0; b < 128; ++b) { s += part[(size_t)b * CH + c]; s2 += partsq[(size_t)b * CH + c]; }
  float m = s * (1.0f / (float)BNTOT);
  float var = s2 * (1.0f / (float)BNTOT) - m * m;
  mu[c] = m;
  rstd[c] = 1.0f / sqrtf(var + 1e-5f);
}

// ---------- K7: BN apply + relu + residual ----------
__global__ void k_out(const float* __restrict__ z, const float* __restrict__ X,
                      const float* __restrict__ mu, const float* __restrict__ rstd,
                      const float* __restrict__ gamma, const float* __restrict__ beta,
                      float* __restrict__ out) {
  int c = threadIdx.x & 63;
  int u = blockIdx.x * 4 + (threadIdx.x >> 6);
  size_t idx = (size_t)u * CH + c;
  float zn = (z[idx] - mu[c]) * rstd[c] * gamma[c] + beta[c];
  out[idx] = fmaxf(zn, 0.f) + X[idx];
}

// ---------- launch ----------
extern "C" void kernel_launch(void* const* d_in, const int* in_sizes, int n_in,
                              void* d_out, int out_size, void* d_ws, size_t ws_size,
                              hipStream_t stream) {
  const float* X     = (const float*)d_in[0];
  const float* W     = (const float*)d_in[1];
  const float* bias  = (const float*)d_in[2];
  const float* gamma = (const float*)d_in[3];
  const float* beta  = (const float*)d_in[4];
  float* out = (float*)d_out;

  // workspace layout (floats unless noted)
  float* ws = (float*)d_ws;
  float* sq     = ws;                    // 8192
  float* t      = sq + 8192;             // 524288
  float* s_loc  = t + 524288;            // 100352
  float* z      = s_loc + 100352;        // 524288
  float* part   = z + 524288;            // 8192
  float* partsq = part + 8192;           // 8192
  float* mu     = partsq + 8192;         // 64
  float* rstd   = mu + 64;               // 64
  float* candv  = rstd + 64;             // 256*64*11 = 180224
  int*   candi  = (int*)(candv + 180224);// 180224 ints
  int*   inds   = candi + 180224;        // 8192*11 = 90112 ints
  // zeroed region: DE (8192 ints) + s_knn (524288 floats), contiguous
  int*   DE     = inds + 90112;
  float* s_knn  = (float*)(DE + 8192);

  hipMemsetAsync(DE, 0, (size_t)(8192 + 524288) * 4, stream);

  k_sq        <<<BNTOT / 4, 256, 0, stream>>>(X, sq);
  k_topk      <<<256, 512, 0, stream>>>(X, sq, candv, candi);
  k_topk_merge<<<32, 256, 0, stream>>>(candv, candi, inds, DE);
  k_lin       <<<128, 256, 0, stream>>>(X, W, bias, t);
  k_scatter   <<<BNTOT / 4, 256, 0, stream>>>(t, inds, s_knn);
  k_local     <<<NLOC / 4, 256, 0, stream>>>(t, s_loc);
  k_gather    <<<BNTOT / 4, 256, 0, stream>>>(s_knn, s_loc, inds, DE, z);
  k_bnpart    <<<128, 256, 0, stream>>>(z, part, partsq);
  k_bnfin     <<<1, 64, 0, stream>>>(part, partsq, mu, rstd);
  k_out       <<<BNTOT / 4, 256, 0, stream>>>(z, X, mu, rstd, gamma, beta, out);

  (void)in_sizes; (void)n_in; (void)out_size; (void)ws_size;
}

// Round 2
// 582.801 us; speedup vs baseline: 1.0210x; 1.0210x over previous
//
#include <hip/hip_runtime.h>
#include <math.h>

#define BNTOT 8192      // B*N
#define CH    64        // channels
#define KP1   11        // K+1 neighbors
#define NLOC  1568      // B * E  (8 * 196)
#define CAP   1024      // per-row candidate capacity
#define MARGIN 2.5f     // bf16 score-error margin for the filter

typedef __attribute__((ext_vector_type(8))) short short8;   // 8 bf16 (4 VGPRs)
typedef __attribute__((ext_vector_type(4))) float float4v;  // MFMA C/D

// ---------- helpers ----------
__device__ __forceinline__ int pcnt(int p) {
  int lo = p - 4; if (lo < 0) lo = 0; lo += (lo & 1);
  int hi = p; if (hi > 26) hi = 26;
  return (hi >= lo) ? (((hi - lo) >> 1) + 1) : 0;
}
__device__ __forceinline__ float dv2_of(int u) {
  int node = u & 1023;
  int rr = node >> 5, cc = node & 31;
  int dv = KP1 + pcnt(rr) * pcnt(cc);
  return 1.0f / sqrtf((float)dv);
}
__device__ __forceinline__ unsigned short f2bf(float f) {   // RNE fp32->bf16
  unsigned u = __float_as_uint(f);
  unsigned r = (u + 0x7FFFu + ((u >> 16) & 1u)) >> 16;
  return (unsigned short)r;
}

// ---------- K0: cast to bf16 + row squared norms (fused) ----------
__global__ void k_cast(const float* __restrict__ X, unsigned short* __restrict__ Xh,
                       float* __restrict__ sq) {
  int g = blockIdx.x * 256 + threadIdx.x;   // one thread per element
  int lane = threadIdx.x & 63;
  float v = X[g];
  Xh[g] = f2bf(v);
  float s = v * v;
  #pragma unroll
  for (int off = 32; off >= 1; off >>= 1) s += __shfl_xor(s, off, 64);
  if (lane == 0) sq[g >> 6] = s;
}

// ---------- KA: per-row threshold from a 256-column sample (exact fp32) ----------
// 128 blocks x 256 thr. lane=row (64 rows/block); wave w scans sample cols
// (w*64+s)*32, s=0..63. Branchless sorted-insert of values only.
__global__ __launch_bounds__(256)
void k_thresh(const float* __restrict__ X, const float* __restrict__ sq,
              float* __restrict__ thr) {
  const int tid = threadIdx.x, wave = tid >> 6, lane = tid & 63;
  const int row = blockIdx.x * 64 + lane;
  float xr[CH];
  {
    const float4* xp = (const float4*)(X + (size_t)row * CH);
    #pragma unroll
    for (int k = 0; k < CH / 4; ++k) {
      float4 v = xp[k];
      xr[4*k+0] = v.x; xr[4*k+1] = v.y; xr[4*k+2] = v.z; xr[4*k+3] = v.w;
    }
  }
  float tv[KP1];
  #pragma unroll
  for (int t = 0; t < KP1; ++t) tv[t] = INFINITY;

  for (int s = 0; s < 64; ++s) {
    int j = __builtin_amdgcn_readfirstlane((wave * 64 + s) * 32);
    const float* cp = X + (size_t)j * CH;
    float d0 = 0.f, d1 = 0.f, d2 = 0.f, d3 = 0.f;
    #pragma unroll
    for (int k = 0; k < CH / 4; ++k) {
      d0 = fmaf(xr[4*k+0], cp[4*k+0], d0);
      d1 = fmaf(xr[4*k+1], cp[4*k+1], d1);
      d2 = fmaf(xr[4*k+2], cp[4*k+2], d2);
      d3 = fmaf(xr[4*k+3], cp[4*k+3], d3);
    }
    float cv = fmaf(-2.0f, (d0 + d1) + (d2 + d3), sq[j]);
    #pragma unroll
    for (int t = 0; t < KP1; ++t) {   // branchless sorted insert (values only)
      float lo = fminf(tv[t], cv), hi = fmaxf(tv[t], cv);
      tv[t] = lo; cv = hi;
    }
  }
  __shared__ float ls[4][64][KP1];
  #pragma unroll
  for (int t = 0; t < KP1; ++t) ls[wave][lane][t] = tv[t];
  __syncthreads();
  if (tid < 64) {
    float v[KP1];
    #pragma unroll
    for (int t = 0; t < KP1; ++t) v[t] = ls[0][tid][t];
    #pragma unroll
    for (int w = 1; w < 4; ++w)
      #pragma unroll
      for (int t = 0; t < KP1; ++t) {
        float cv = ls[w][tid][t];
        #pragma unroll
        for (int s2 = 0; s2 < KP1; ++s2) {
          float lo = fminf(v[s2], cv), hi = fmaxf(v[s2], cv);
          v[s2] = lo; cv = hi;
        }
      }
    thr[blockIdx.x * 64 + tid] = v[KP1 - 1] + MARGIN;
  }
}

// ---------- KB: MFMA all-pairs scores + threshold filter -> candidate lists ----------
// grid 512 = 64 row-tiles(128 rows) x 8 col-tiles(1024 cols); block 256 = 4 waves.
// wave = 256-col strip x all 128 rows. 16x16x32 bf16 MFMA, K=64 in 2 steps.
__global__ __launch_bounds__(256, 2)
void k_filter(const unsigned short* __restrict__ Xh, const float* __restrict__ sq,
              const float* __restrict__ thr, int* __restrict__ cnt,
              unsigned short* __restrict__ cand) {
  const int tid = threadIdx.x, wave = tid >> 6, lane = tid & 63;
  const int m = lane & 15, q = lane >> 4;
  const int rowbase = (blockIdx.x >> 3) * 128;
  const int colbase = (blockIdx.x & 7) * 1024 + wave * 256;

  // A fragments: 8 row-subtiles x 2 k-chunks
  short8 a[8][2];
  #pragma unroll
  for (int rt = 0; rt < 8; ++rt)
    #pragma unroll
    for (int kc = 0; kc < 2; ++kc)
      a[rt][kc] = *(const short8*)(Xh + (size_t)(rowbase + rt * 16 + m) * CH + kc * 32 + q * 8);

  // per-lane thresholds for the 32 (rt, reg) rows this lane's C-regs cover
  float thrv[32];
  #pragma unroll
  for (int rt = 0; rt < 8; ++rt)
    #pragma unroll
    for (int r = 0; r < 4; ++r)
      thrv[rt * 4 + r] = thr[rowbase + rt * 16 + q * 4 + r];

  const float4v cz = {0.f, 0.f, 0.f, 0.f};
  for (int sub = 0; sub < 16; ++sub) {
    const int coln = colbase + sub * 16 + m;
    const short8* bp = (const short8*)(Xh + (size_t)coln * CH + q * 8);
    short8 b0 = bp[0];
    short8 b1 = bp[4];               // +32 bf16
    float sqc = sq[coln];
    #pragma unroll
    for (int rt = 0; rt < 8; ++rt) {
      float4v c = __builtin_amdgcn_mfma_f32_16x16x32_bf16(a[rt][0], b0, cz, 0, 0, 0);
      c = __builtin_amdgcn_mfma_f32_16x16x32_bf16(a[rt][1], b1, c, 0, 0, 0);
      #pragma unroll
      for (int r = 0; r < 4; ++r) {
        float score = fmaf(-2.0f, c[r], sqc);
        if (score < thrv[rt * 4 + r]) {
          int row = rowbase + rt * 16 + q * 4 + r;
          int slot = atomicAdd(&cnt[row], 1);
          if (slot < CAP) cand[(size_t)row * CAP + slot] = (unsigned short)coln;
        }
      }
    }
  }
}

// ---------- KC: exact fp32 rescore of candidates + top-11 + DE ----------
// 512 blocks x 256 thr; 16 rows/block, 16 lanes/row.
__global__ __launch_bounds__(256)
void k_rescore(const float* __restrict__ X, const float* __restrict__ sq,
               const int* __restrict__ cnt, const unsigned short* __restrict__ cand,
               int* __restrict__ inds, int* __restrict__ DE) {
  const int tid = threadIdx.x, wave = tid >> 6, lane = tid & 63;
  const int ph = lane & 15, rl = lane >> 4;
  const int row = blockIdx.x * 16 + wave * 4 + rl;

  float xr[CH];
  {
    const float4* xp = (const float4*)(X + (size_t)row * CH);
    #pragma unroll
    for (int k = 0; k < CH / 4; ++k) {
      float4 v = xp[k];
      xr[4*k+0] = v.x; xr[4*k+1] = v.y; xr[4*k+2] = v.z; xr[4*k+3] = v.w;
    }
  }
  int n = cnt[row]; if (n > CAP) n = CAP;

  float tv[KP1]; int ti[KP1];
  #pragma unroll
  for (int t = 0; t < KP1; ++t) { tv[t] = INFINITY; ti[t] = -1; }

  for (int s = ph; s < n; s += 16) {
    int cj = cand[(size_t)row * CAP + s];
    const float4* cp = (const float4*)(X + (size_t)cj * CH);
    float d0 = 0.f, d1 = 0.f, d2 = 0.f, d3 = 0.f;
    #pragma unroll
    for (int k = 0; k < CH / 4; ++k) {
      float4 v = cp[k];
      d0 = fmaf(xr[4*k+0], v.x, d0);
      d1 = fmaf(xr[4*k+1], v.y, d1);
      d2 = fmaf(xr[4*k+2], v.z, d2);
      d3 = fmaf(xr[4*k+3], v.w, d3);
    }
    float score = fmaf(-2.0f, (d0 + d1) + (d2 + d3), sq[cj]);
    if (score < tv[KP1 - 1]) {
      float cv = score; int ci = cj;
      #pragma unroll
      for (int t = 0; t < KP1; ++t) {
        bool sw = cv < tv[t];
        float nv = sw ? cv   : tv[t]; int ni = sw ? ci   : ti[t];
        float ov = sw ? tv[t] : cv;   int oi = sw ? ti[t] : ci;
        tv[t] = nv; ti[t] = ni; cv = ov; ci = oi;
      }
    }
  }
  __shared__ float lv[256][KP1];
  __shared__ int   li[256][KP1];
  #pragma unroll
  for (int t = 0; t < KP1; ++t) { lv[tid][t] = tv[t]; li[tid][t] = ti[t]; }
  __syncthreads();
  if (tid < 16) {
    const int r = tid;
    const int base = (r >> 2) * 64 + (r & 3) * 16;   // wave*64 + rl*16
    float v[KP1]; int id[KP1];
    #pragma unroll
    for (int t = 0; t < KP1; ++t) { v[t] = lv[base][t]; id[t] = li[base][t]; }
    for (int j = 1; j < 16; ++j) {
      #pragma unroll
      for (int t = 0; t < KP1; ++t) {
        float cv = lv[base + j][t]; int ci = li[base + j][t];
        if (cv < v[KP1 - 1]) {
          #pragma unroll
          for (int s2 = 0; s2 < KP1; ++s2) {
            bool sw = cv < v[s2];
            float nv = sw ? cv    : v[s2]; int ni = sw ? ci     : id[s2];
            float ov = sw ? v[s2] : cv;    int oi = sw ? id[s2] : ci;
            v[s2] = nv; id[s2] = ni; cv = ov; ci = oi;
          }
        }
      }
    }
    int orow = blockIdx.x * 16 + r;
    #pragma unroll
    for (int t = 0; t < KP1; ++t) {
      inds[orow * KP1 + t] = id[t];
      atomicAdd(&DE[id[t]], 1);
    }
  }
}

// ---------- K3: t = Dv^{-1/2} * (x @ W^T + b) ----------
__global__ void k_lin(const float* __restrict__ X, const float* __restrict__ W,
                      const float* __restrict__ bias, float* __restrict__ t) {
  int lane = threadIdx.x & 63;
  int wave = threadIdx.x >> 6;
  int rowbase = (blockIdx.x * 4 + wave) * 16;
  float wr[CH];
  {
    const float4* wp = (const float4*)(W + (size_t)lane * CH);
    #pragma unroll
    for (int k = 0; k < CH / 4; ++k) {
      float4 v = wp[k];
      wr[4*k+0] = v.x; wr[4*k+1] = v.y; wr[4*k+2] = v.z; wr[4*k+3] = v.w;
    }
  }
  float bc = bias[lane];
  for (int r = 0; r < 16; ++r) {
    int row = __builtin_amdgcn_readfirstlane(rowbase + r);
    const float* xp = X + (size_t)row * CH;
    float d0 = 0.f, d1 = 0.f, d2 = 0.f, d3 = 0.f;
    #pragma unroll
    for (int k = 0; k < CH / 4; ++k) {
      d0 = fmaf(wr[4*k+0], xp[4*k+0], d0);
      d1 = fmaf(wr[4*k+1], xp[4*k+1], d1);
      d2 = fmaf(wr[4*k+2], xp[4*k+2], d2);
      d3 = fmaf(wr[4*k+3], xp[4*k+3], d3);
    }
    float y = (d0 + d1) + (d2 + d3) + bc;
    t[(size_t)row * CH + lane] = y * dv2_of(row);
  }
}

// ---------- K4a: scatter t into KNN edge sums ----------
__global__ void k_scatter(const float* __restrict__ t, const int* __restrict__ inds,
                          float* __restrict__ s_knn) {
  int c = threadIdx.x & 63;
  int u = blockIdx.x * 4 + (threadIdx.x >> 6);
  float val = t[(size_t)u * CH + c];
  int ub = __builtin_amdgcn_readfirstlane(u);
  const int* ip = inds + (size_t)ub * KP1;
  #pragma unroll
  for (int j = 0; j < KP1; ++j) {
    int e = ip[j];
    atomicAdd(&s_knn[(size_t)e * CH + c], val);
  }
}

// ---------- K4b: local patch edge sums, pre-scaled by 1/De (=1/25) ----------
__global__ void k_local(const float* __restrict__ t, float* __restrict__ s_loc) {
  int c = threadIdx.x & 63;
  int e = blockIdx.x * 4 + (threadIdx.x >> 6);
  int b  = e / 196;
  int le = e - b * 196;
  int pi = le / 14;
  int pj = le - pi * 14;
  int base = b * 1024 + (pi * 2) * 32 + pj * 2;
  float acc = 0.f;
  #pragma unroll
  for (int di = 0; di < 5; ++di)
    #pragma unroll
    for (int dj = 0; dj < 5; ++dj)
      acc += t[(size_t)(base + di * 32 + dj) * CH + c];
  s_loc[(size_t)e * CH + c] = acc * (1.0f / 25.0f);
}

// ---------- K5: z[u] = dv2_u * ( sum_knn s_knn[e]/DE[e] + sum_local s_loc[p] ) ----------
__global__ void k_gather(const float* __restrict__ s_knn, const float* __restrict__ s_loc,
                         const int* __restrict__ inds, const int* __restrict__ DE,
                         float* __restrict__ z) {
  int c = threadIdx.x & 63;
  int u = blockIdx.x * 4 + (threadIdx.x >> 6);
  int ub = __builtin_amdgcn_readfirstlane(u);
  const int* ip = inds + (size_t)ub * KP1;
  float acc = 0.f;
  #pragma unroll
  for (int j = 0; j < KP1; ++j) {
    int e = ip[j];
    float invde = 1.0f / (float)DE[e];
    acc += s_knn[(size_t)e * CH + c] * invde;
  }
  int node = ub & 1023, b = ub >> 10;
  int rr = node >> 5, cc = node & 31;
  int i0 = rr - 4; if (i0 < 0) i0 = 0; i0 += (i0 & 1);
  int i1 = rr; if (i1 > 26) i1 = 26;
  int j0 = cc - 4; if (j0 < 0) j0 = 0; j0 += (j0 & 1);
  int j1 = cc; if (j1 > 26) j1 = 26;
  for (int i = i0; i <= i1; i += 2)
    for (int jj = j0; jj <= j1; jj += 2) {
      int e = b * 196 + (i >> 1) * 14 + (jj >> 1);
      acc += s_loc[(size_t)e * CH + c];
    }
  z[(size_t)ub * CH + c] = acc * dv2_of(ub);
}

// ---------- K6a: per-64-row-block partial BN sums ----------
__global__ void k_bnpart(const float* __restrict__ z, float* __restrict__ part,
                         float* __restrict__ partsq) {
  int c = threadIdx.x & 63;
  int rq = threadIdx.x >> 6;
  int blk = blockIdx.x;
  float s = 0.f, s2 = 0.f;
  for (int k = 0; k < 16; ++k) {
    float v = z[(size_t)(blk * 64 + rq * 16 + k) * CH + c];
    s += v; s2 += v * v;
  }
  __shared__ float ls[4][CH], ls2[4][CH];
  ls[rq][c] = s; ls2[rq][c] = s2;
  __syncthreads();
  if (rq == 0) {
    part[(size_t)blk * CH + c]   = ls[0][c] + ls[1][c] + ls[2][c] + ls[3][c];
    partsq[(size_t)blk * CH + c] = ls2[0][c] + ls2[1][c] + ls2[2][c] + ls2[3][c];
  }
}

// ---------- K6b: finalize mu / rstd ----------
__global__ void k_bnfin(const float* __restrict__ part, const float* __restrict__ partsq,
                        float* __restrict__ mu, float* __restrict__ rstd) {
  int c = threadIdx.x;
  float s = 0.f, s2 = 0.f;
  for (int b = 0; b < 128; ++b) { s += part[(size_t)b * CH + c]; s2 += partsq[(size_t)b * CH + c]; }
  float m = s * (1.0f / (float)BNTOT);
  float var = s2 * (1.0f / (float)BNTOT) - m * m;
  mu[c] = m;
  rstd[c] = 1.0f / sqrtf(var + 1e-5f);
}

// ---------- K7: BN apply + relu + residual ----------
__global__ void k_out(const float* __restrict__ z, const float* __restrict__ X,
                      const float* __restrict__ mu, const float* __restrict__ rstd,
                      const float* __restrict__ gamma, const float* __restrict__ beta,
                      float* __restrict__ out) {
  int c = threadIdx.x & 63;
  int u = blockIdx.x * 4 + (threadIdx.x >> 6);
  size_t idx = (size_t)u * CH + c;
  float zn = (z[idx] - mu[c]) * rstd[c] * gamma[c] + beta[c];
  out[idx] = fmaxf(zn, 0.f) + X[idx];
}

// ---------- launch ----------
extern "C" void kernel_launch(void* const* d_in, const int* in_sizes, int n_in,
                              void* d_out, int out_size, void* d_ws, size_t ws_size,
                              hipStream_t stream) {
  const float* X     = (const float*)d_in[0];
  const float* W     = (const float*)d_in[1];
  const float* bias  = (const float*)d_in[2];
  const float* gamma = (const float*)d_in[3];
  const float* beta  = (const float*)d_in[4];
  float* out = (float*)d_out;

  // workspace layout
  float* ws = (float*)d_ws;
  float* sq     = ws;                       // 8192
  float* thr    = sq + 8192;                // 8192
  float* t      = thr + 8192;               // 524288
  float* s_loc  = t + 524288;               // 100352
  float* z      = s_loc + 100352;           // 524288
  float* part   = z + 524288;               // 8192
  float* partsq = part + 8192;              // 8192
  float* mu     = partsq + 8192;            // 64
  float* rstd   = mu + 64;                  // 64
  int*   inds   = (int*)(rstd + 64);        // 90112 ints
  unsigned short* Xh   = (unsigned short*)(inds + 90112);   // 524288 shorts
  unsigned short* cand = Xh + 524288;                        // 8192*1024 shorts
  // zeroed region: cnt (8192 int) + DE (8192 int) + s_knn (524288 f), contiguous
  int*   cnt    = (int*)(cand + (size_t)8192 * CAP);
  int*   DE     = cnt + 8192;
  float* s_knn  = (float*)(DE + 8192);

  hipMemsetAsync(cnt, 0, (size_t)(8192 + 8192 + 524288) * 4, stream);

  k_cast    <<<2048, 256, 0, stream>>>(X, Xh, sq);
  k_thresh  <<<128, 256, 0, stream>>>(X, sq, thr);
  k_filter  <<<512, 256, 0, stream>>>(Xh, sq, thr, cnt, cand);
  k_rescore <<<512, 256, 0, stream>>>(X, sq, cnt, cand, inds, DE);
  k_lin     <<<128, 256, 0, stream>>>(X, W, bias, t);
  k_scatter <<<BNTOT / 4, 256, 0, stream>>>(t, inds, s_knn);
  k_local   <<<NLOC / 4, 256, 0, stream>>>(t, s_loc);
  k_gather  <<<BNTOT / 4, 256, 0, stream>>>(s_knn, s_loc, inds, DE, z);
  k_bnpart  <<<128, 256, 0, stream>>>(z, part, partsq);
  k_bnfin   <<<1, 64, 0, stream>>>(part, partsq, mu, rstd);
  k_out     <<<BNTOT / 4, 256, 0, stream>>>(z, X, mu, rstd, gamma, beta, out);

  (void)in_sizes; (void)n_in; (void)out_size; (void)ws_size;
}

// Round 3
// 334.131 us; speedup vs baseline: 1.7809x; 1.7442x over previous
//
#include <hip/hip_runtime.h>
#include <math.h>

#define BNTOT 8192      // B*N
#define CH    64        // channels
#define KP1   11        // K+1 neighbors
#define NLOC  1568      // B * E  (8 * 196)
#define CAP   1024      // per-row global candidate capacity
#define LCAP  64        // per-row per-block LDS candidate capacity
#define MARGIN 2.5f     // bf16 score-error margin for the filter

typedef __attribute__((ext_vector_type(8))) short short8;   // 8 bf16 (4 VGPRs)
typedef __attribute__((ext_vector_type(4))) float float4v;  // MFMA C/D

// ---------- helpers ----------
__device__ __forceinline__ int pcnt(int p) {
  int lo = p - 4; if (lo < 0) lo = 0; lo += (lo & 1);
  int hi = p; if (hi > 26) hi = 26;
  return (hi >= lo) ? (((hi - lo) >> 1) + 1) : 0;
}
__device__ __forceinline__ float dv2_of(int u) {
  int node = u & 1023;
  int rr = node >> 5, cc = node & 31;
  int dv = KP1 + pcnt(rr) * pcnt(cc);
  return 1.0f / sqrtf((float)dv);
}
__device__ __forceinline__ unsigned short f2bf(float f) {   // RNE fp32->bf16
  unsigned u = __float_as_uint(f);
  unsigned r = (u + 0x7FFFu + ((u >> 16) & 1u)) >> 16;
  return (unsigned short)r;
}

// ---------- K0: cast to bf16 + row squared norms (fused) ----------
__global__ void k_cast(const float* __restrict__ X, unsigned short* __restrict__ Xh,
                       float* __restrict__ sq) {
  int g = blockIdx.x * 256 + threadIdx.x;
  int lane = threadIdx.x & 63;
  float v = X[g];
  Xh[g] = f2bf(v);
  float s = v * v;
  #pragma unroll
  for (int off = 32; off >= 1; off >>= 1) s += __shfl_xor(s, off, 64);
  if (lane == 0) sq[g >> 6] = s;
}

// ---------- KA: per-row threshold from a 1024-column sample (exact fp32) ----------
// 128 blocks x 512 thr (8 waves). lane = row (64 rows/block); wave w scans
// sample cols (w*128+s)*8, s=0..127. Branchless sorted-insert (values only).
__global__ __launch_bounds__(512)
void k_thresh(const float* __restrict__ X, const float* __restrict__ sq,
              float* __restrict__ thr) {
  const int tid = threadIdx.x, wave = tid >> 6, lane = tid & 63;
  const int row = blockIdx.x * 64 + lane;
  float xr[CH];
  {
    const float4* xp = (const float4*)(X + (size_t)row * CH);
    #pragma unroll
    for (int k = 0; k < CH / 4; ++k) {
      float4 v = xp[k];
      xr[4*k+0] = v.x; xr[4*k+1] = v.y; xr[4*k+2] = v.z; xr[4*k+3] = v.w;
    }
  }
  float tv[KP1];
  #pragma unroll
  for (int t = 0; t < KP1; ++t) tv[t] = INFINITY;

  for (int s = 0; s < 128; ++s) {
    int j = __builtin_amdgcn_readfirstlane((wave * 128 + s) * 8);
    const float* cp = X + (size_t)j * CH;
    float d0 = 0.f, d1 = 0.f, d2 = 0.f, d3 = 0.f;
    #pragma unroll
    for (int k = 0; k < CH / 4; ++k) {
      d0 = fmaf(xr[4*k+0], cp[4*k+0], d0);
      d1 = fmaf(xr[4*k+1], cp[4*k+1], d1);
      d2 = fmaf(xr[4*k+2], cp[4*k+2], d2);
      d3 = fmaf(xr[4*k+3], cp[4*k+3], d3);
    }
    float cv = fmaf(-2.0f, (d0 + d1) + (d2 + d3), sq[j]);
    #pragma unroll
    for (int t = 0; t < KP1; ++t) {
      float lo = fminf(tv[t], cv), hi = fmaxf(tv[t], cv);
      tv[t] = lo; cv = hi;
    }
  }
  __shared__ float ls[8][64][KP1];
  #pragma unroll
  for (int t = 0; t < KP1; ++t) ls[wave][lane][t] = tv[t];
  __syncthreads();
  if (tid < 64) {
    float v[KP1];
    #pragma unroll
    for (int t = 0; t < KP1; ++t) v[t] = ls[0][tid][t];
    #pragma unroll
    for (int w = 1; w < 8; ++w)
      #pragma unroll
      for (int t = 0; t < KP1; ++t) {
        float cv = ls[w][tid][t];
        #pragma unroll
        for (int s2 = 0; s2 < KP1; ++s2) {
          float lo = fminf(v[s2], cv), hi = fmaxf(v[s2], cv);
          v[s2] = lo; cv = hi;
        }
      }
    thr[blockIdx.x * 64 + tid] = v[KP1 - 1] + MARGIN;
  }
}

// ---------- KB: MFMA all-pairs scores + filter -> LDS compaction -> packed cand ----------
// grid 512 = 64 row-tiles(128 rows) x 8 col-tiles(1024 cols); block 256 = 4 waves.
__global__ __launch_bounds__(256, 2)
void k_filter(const unsigned short* __restrict__ Xh, const float* __restrict__ sq,
              const float* __restrict__ thr, int* __restrict__ cnt,
              unsigned short* __restrict__ cand) {
  __shared__ unsigned short lcand[128][LCAP + 2];   // +2 pad: conflict-free epilogue
  __shared__ int lcnt[128];
  __shared__ int lbase[128];

  const int tid = threadIdx.x, wave = tid >> 6, lane = tid & 63;
  const int m = lane & 15, q = lane >> 4;
  const int rowbase = (blockIdx.x >> 3) * 128;
  const int colbase = (blockIdx.x & 7) * 1024 + wave * 256;

  if (tid < 128) lcnt[tid] = 0;

  // A fragments: 8 row-subtiles x 2 k-chunks
  short8 a[8][2];
  #pragma unroll
  for (int rt = 0; rt < 8; ++rt)
    #pragma unroll
    for (int kc = 0; kc < 2; ++kc)
      a[rt][kc] = *(const short8*)(Xh + (size_t)(rowbase + rt * 16 + m) * CH + kc * 32 + q * 8);

  float thrv[32];
  #pragma unroll
  for (int rt = 0; rt < 8; ++rt)
    #pragma unroll
    for (int r = 0; r < 4; ++r)
      thrv[rt * 4 + r] = thr[rowbase + rt * 16 + q * 4 + r];

  __syncthreads();

  const float4v cz = {0.f, 0.f, 0.f, 0.f};
  for (int sub = 0; sub < 16; ++sub) {
    const int coln = colbase + sub * 16 + m;
    const short8* bp = (const short8*)(Xh + (size_t)coln * CH + q * 8);
    short8 b0 = bp[0];
    short8 b1 = bp[4];               // +32 bf16
    float sqc = sq[coln];
    #pragma unroll
    for (int rt = 0; rt < 8; ++rt) {
      float4v c = __builtin_amdgcn_mfma_f32_16x16x32_bf16(a[rt][0], b0, cz, 0, 0, 0);
      c = __builtin_amdgcn_mfma_f32_16x16x32_bf16(a[rt][1], b1, c, 0, 0, 0);
      #pragma unroll
      for (int r = 0; r < 4; ++r) {
        float score = fmaf(-2.0f, c[r], sqc);
        if (score < thrv[rt * 4 + r]) {
          int rl = rt * 16 + q * 4 + r;
          int s = atomicAdd(&lcnt[rl], 1);
          if (s < LCAP) {
            lcand[rl][s] = (unsigned short)coln;
          } else {                                   // rare overflow: direct global
            int gs = atomicAdd(&cnt[rowbase + rl], 1);
            if (gs < CAP) cand[(size_t)(rowbase + rl) * CAP + gs] = (unsigned short)coln;
          }
        }
      }
    }
  }

  __syncthreads();
  if (tid < 128) {
    int nl = lcnt[tid]; if (nl > LCAP) nl = LCAP;
    lbase[tid] = atomicAdd(&cnt[rowbase + tid], nl);
    lcnt[tid] = nl;
  }
  __syncthreads();
  if (tid < 128) {
    int nl = lcnt[tid], base = lbase[tid];
    unsigned short* dst = cand + (size_t)(rowbase + tid) * CAP;
    for (int s = 0; s < nl; ++s) {
      int g = base + s;
      if (g < CAP) dst[g] = lcand[tid][s];
    }
  }
}

// ---------- KC: exact fp32 rescore of candidates + top-11 + DE ----------
// 512 blocks x 256 thr; 16 rows/block, 16 lanes/row.
__global__ __launch_bounds__(256)
void k_rescore(const float* __restrict__ X, const float* __restrict__ sq,
               const int* __restrict__ cnt, const unsigned short* __restrict__ cand,
               int* __restrict__ inds, int* __restrict__ DE) {
  const int tid = threadIdx.x, wave = tid >> 6, lane = tid & 63;
  const int ph = lane & 15, rl = lane >> 4;
  const int row = blockIdx.x * 16 + wave * 4 + rl;

  float xr[CH];
  {
    const float4* xp = (const float4*)(X + (size_t)row * CH);
    #pragma unroll
    for (int k = 0; k < CH / 4; ++k) {
      float4 v = xp[k];
      xr[4*k+0] = v.x; xr[4*k+1] = v.y; xr[4*k+2] = v.z; xr[4*k+3] = v.w;
    }
  }
  int n = cnt[row]; if (n > CAP) n = CAP;

  float tv[KP1]; int ti[KP1];
  #pragma unroll
  for (int t = 0; t < KP1; ++t) { tv[t] = INFINITY; ti[t] = -1; }

  for (int s = ph; s < n; s += 16) {
    int cj = cand[(size_t)row * CAP + s];
    const float4* cp = (const float4*)(X + (size_t)cj * CH);
    float d0 = 0.f, d1 = 0.f, d2 = 0.f, d3 = 0.f;
    #pragma unroll
    for (int k = 0; k < CH / 4; ++k) {
      float4 v = cp[k];
      d0 = fmaf(xr[4*k+0], v.x, d0);
      d1 = fmaf(xr[4*k+1], v.y, d1);
      d2 = fmaf(xr[4*k+2], v.z, d2);
      d3 = fmaf(xr[4*k+3], v.w, d3);
    }
    float score = fmaf(-2.0f, (d0 + d1) + (d2 + d3), sq[cj]);
    if (score < tv[KP1 - 1]) {
      float cv = score; int ci = cj;
      #pragma unroll
      for (int t = 0; t < KP1; ++t) {
        bool sw = cv < tv[t];
        float nv = sw ? cv   : tv[t]; int ni = sw ? ci   : ti[t];
        float ov = sw ? tv[t] : cv;   int oi = sw ? ti[t] : ci;
        tv[t] = nv; ti[t] = ni; cv = ov; ci = oi;
      }
    }
  }
  __shared__ float lv[256][KP1];
  __shared__ int   li[256][KP1];
  #pragma unroll
  for (int t = 0; t < KP1; ++t) { lv[tid][t] = tv[t]; li[tid][t] = ti[t]; }
  __syncthreads();
  if (tid < 16) {
    const int r = tid;
    const int base = (r >> 2) * 64 + (r & 3) * 16;   // wave*64 + rl*16
    float v[KP1]; int id[KP1];
    #pragma unroll
    for (int t = 0; t < KP1; ++t) { v[t] = lv[base][t]; id[t] = li[base][t]; }
    for (int j = 1; j < 16; ++j) {
      #pragma unroll
      for (int t = 0; t < KP1; ++t) {
        float cv = lv[base + j][t]; int ci = li[base + j][t];
        if (cv < v[KP1 - 1]) {
          #pragma unroll
          for (int s2 = 0; s2 < KP1; ++s2) {
            bool sw = cv < v[s2];
            float nv = sw ? cv    : v[s2]; int ni = sw ? ci     : id[s2];
            float ov = sw ? v[s2] : cv;    int oi = sw ? id[s2] : ci;
            v[s2] = nv; id[s2] = ni; cv = ov; ci = oi;
          }
        }
      }
    }
    int orow = blockIdx.x * 16 + r;
    #pragma unroll
    for (int t = 0; t < KP1; ++t) {
      inds[orow * KP1 + t] = id[t];
      atomicAdd(&DE[id[t]], 1);
    }
  }
}

// ---------- K3: t = Dv^{-1/2} * (x @ W^T + b) ----------
__global__ void k_lin(const float* __restrict__ X, const float* __restrict__ W,
                      const float* __restrict__ bias, float* __restrict__ t) {
  int lane = threadIdx.x & 63;
  int wave = threadIdx.x >> 6;
  int rowbase = (blockIdx.x * 4 + wave) * 16;
  float wr[CH];
  {
    const float4* wp = (const float4*)(W + (size_t)lane * CH);
    #pragma unroll
    for (int k = 0; k < CH / 4; ++k) {
      float4 v = wp[k];
      wr[4*k+0] = v.x; wr[4*k+1] = v.y; wr[4*k+2] = v.z; wr[4*k+3] = v.w;
    }
  }
  float bc = bias[lane];
  for (int r = 0; r < 16; ++r) {
    int row = __builtin_amdgcn_readfirstlane(rowbase + r);
    const float* xp = X + (size_t)row * CH;
    float d0 = 0.f, d1 = 0.f, d2 = 0.f, d3 = 0.f;
    #pragma unroll
    for (int k = 0; k < CH / 4; ++k) {
      d0 = fmaf(wr[4*k+0], xp[4*k+0], d0);
      d1 = fmaf(wr[4*k+1], xp[4*k+1], d1);
      d2 = fmaf(wr[4*k+2], xp[4*k+2], d2);
      d3 = fmaf(wr[4*k+3], xp[4*k+3], d3);
    }
    float y = (d0 + d1) + (d2 + d3) + bc;
    t[(size_t)row * CH + lane] = y * dv2_of(row);
  }
}

// ---------- K4a: scatter t into KNN edge sums ----------
__global__ void k_scatter(const float* __restrict__ t, const int* __restrict__ inds,
                          float* __restrict__ s_knn) {
  int c = threadIdx.x & 63;
  int u = blockIdx.x * 4 + (threadIdx.x >> 6);
  float val = t[(size_t)u * CH + c];
  int ub = __builtin_amdgcn_readfirstlane(u);
  const int* ip = inds + (size_t)ub * KP1;
  #pragma unroll
  for (int j = 0; j < KP1; ++j) {
    int e = ip[j];
    atomicAdd(&s_knn[(size_t)e * CH + c], val);
  }
}

// ---------- K4b: local patch edge sums, pre-scaled by 1/De (=1/25) ----------
__global__ void k_local(const float* __restrict__ t, float* __restrict__ s_loc) {
  int c = threadIdx.x & 63;
  int e = blockIdx.x * 4 + (threadIdx.x >> 6);
  int b  = e / 196;
  int le = e - b * 196;
  int pi = le / 14;
  int pj = le - pi * 14;
  int base = b * 1024 + (pi * 2) * 32 + pj * 2;
  float acc = 0.f;
  #pragma unroll
  for (int di = 0; di < 5; ++di)
    #pragma unroll
    for (int dj = 0; dj < 5; ++dj)
      acc += t[(size_t)(base + di * 32 + dj) * CH + c];
  s_loc[(size_t)e * CH + c] = acc * (1.0f / 25.0f);
}

// ---------- K5: z[u] = dv2_u * ( sum_knn s_knn[e]/DE[e] + sum_local s_loc[p] ) ----------
__global__ void k_gather(const float* __restrict__ s_knn, const float* __restrict__ s_loc,
                         const int* __restrict__ inds, const int* __restrict__ DE,
                         float* __restrict__ z) {
  int c = threadIdx.x & 63;
  int u = blockIdx.x * 4 + (threadIdx.x >> 6);
  int ub = __builtin_amdgcn_readfirstlane(u);
  const int* ip = inds + (size_t)ub * KP1;
  float acc = 0.f;
  #pragma unroll
  for (int j = 0; j < KP1; ++j) {
    int e = ip[j];
    float invde = 1.0f / (float)DE[e];
    acc += s_knn[(size_t)e * CH + c] * invde;
  }
  int node = ub & 1023, b = ub >> 10;
  int rr = node >> 5, cc = node & 31;
  int i0 = rr - 4; if (i0 < 0) i0 = 0; i0 += (i0 & 1);
  int i1 = rr; if (i1 > 26) i1 = 26;
  int j0 = cc - 4; if (j0 < 0) j0 = 0; j0 += (j0 & 1);
  int j1 = cc; if (j1 > 26) j1 = 26;
  for (int i = i0; i <= i1; i += 2)
    for (int jj = j0; jj <= j1; jj += 2) {
      int e = b * 196 + (i >> 1) * 14 + (jj >> 1);
      acc += s_loc[(size_t)e * CH + c];
    }
  z[(size_t)ub * CH + c] = acc * dv2_of(ub);
}

// ---------- K6a: per-64-row-block partial BN sums ----------
__global__ void k_bnpart(const float* __restrict__ z, float* __restrict__ part,
                         float* __restrict__ partsq) {
  int c = threadIdx.x & 63;
  int rq = threadIdx.x >> 6;
  int blk = blockIdx.x;
  float s = 0.f, s2 = 0.f;
  for (int k = 0; k < 16; ++k) {
    float v = z[(size_t)(blk * 64 + rq * 16 + k) * CH + c];
    s += v; s2 += v * v;
  }
  __shared__ float ls[4][CH], ls2[4][CH];
  ls[rq][c] = s; ls2[rq][c] = s2;
  __syncthreads();
  if (rq == 0) {
    part[(size_t)blk * CH + c]   = ls[0][c] + ls[1][c] + ls[2][c] + ls[3][c];
    partsq[(size_t)blk * CH + c] = ls2[0][c] + ls2[1][c] + ls2[2][c] + ls2[3][c];
  }
}

// ---------- K6b: finalize mu / rstd ----------
__global__ void k_bnfin(const float* __restrict__ part, const float* __restrict__ partsq,
                        float* __restrict__ mu, float* __restrict__ rstd) {
  int c = threadIdx.x;
  float s = 0.f, s2 = 0.f;
  for (int b = 0; b < 128; ++b) { s += part[(size_t)b * CH + c]; s2 += partsq[(size_t)b * CH + c]; }
  float m = s * (1.0f / (float)BNTOT);
  float var = s2 * (1.0f / (float)BNTOT) - m * m;
  mu[c] = m;
  rstd[c] = 1.0f / sqrtf(var + 1e-5f);
}

// ---------- K7: BN apply + relu + residual ----------
__global__ void k_out(const float* __restrict__ z, const float* __restrict__ X,
                      const float* __restrict__ mu, const float* __restrict__ rstd,
                      const float* __restrict__ gamma, const float* __restrict__ beta,
                      float* __restrict__ out) {
  int c = threadIdx.x & 63;
  int u = blockIdx.x * 4 + (threadIdx.x >> 6);
  size_t idx = (size_t)u * CH + c;
  float zn = (z[idx] - mu[c]) * rstd[c] * gamma[c] + beta[c];
  out[idx] = fmaxf(zn, 0.f) + X[idx];
}

// ---------- launch ----------
extern "C" void kernel_launch(void* const* d_in, const int* in_sizes, int n_in,
                              void* d_out, int out_size, void* d_ws, size_t ws_size,
                              hipStream_t stream) {
  const float* X     = (const float*)d_in[0];
  const float* W     = (const float*)d_in[1];
  const float* bias  = (const float*)d_in[2];
  const float* gamma = (const float*)d_in[3];
  const float* beta  = (const float*)d_in[4];
  float* out = (float*)d_out;

  // workspace layout
  float* ws = (float*)d_ws;
  float* sq     = ws;                       // 8192
  float* thr    = sq + 8192;                // 8192
  float* t      = thr + 8192;               // 524288
  float* s_loc  = t + 524288;               // 100352
  float* z      = s_loc + 100352;           // 524288
  float* part   = z + 524288;               // 8192
  float* partsq = part + 8192;              // 8192
  float* mu     = partsq + 8192;            // 64
  float* rstd   = mu + 64;                  // 64
  int*   inds   = (int*)(rstd + 64);        // 90112 ints
  unsigned short* Xh   = (unsigned short*)(inds + 90112);   // 524288 shorts
  unsigned short* cand = Xh + 524288;                        // 8192*1024 shorts
  // zeroed region: cnt (8192 int) + DE (8192 int) + s_knn (524288 f), contiguous
  int*   cnt    = (int*)(cand + (size_t)8192 * CAP);
  int*   DE     = cnt + 8192;
  float* s_knn  = (float*)(DE + 8192);

  hipMemsetAsync(cnt, 0, (size_t)(8192 + 8192 + 524288) * 4, stream);

  k_cast    <<<2048, 256, 0, stream>>>(X, Xh, sq);
  k_thresh  <<<128, 512, 0, stream>>>(X, sq, thr);
  k_filter  <<<512, 256, 0, stream>>>(Xh, sq, thr, cnt, cand);
  k_rescore <<<512, 256, 0, stream>>>(X, sq, cnt, cand, inds, DE);
  k_lin     <<<128, 256, 0, stream>>>(X, W, bias, t);
  k_scatter <<<BNTOT / 4, 256, 0, stream>>>(t, inds, s_knn);
  k_local   <<<NLOC / 4, 256, 0, stream>>>(t, s_loc);
  k_gather  <<<BNTOT / 4, 256, 0, stream>>>(s_knn, s_loc, inds, DE, z);
  k_bnpart  <<<128, 256, 0, stream>>>(z, part, partsq);
  k_bnfin   <<<1, 64, 0, stream>>>(part, partsq, mu, rstd);
  k_out     <<<BNTOT / 4, 256, 0, stream>>>(z, X, mu, rstd, gamma, beta, out);

  (void)in_sizes; (void)n_in; (void)out_size; (void)ws_size;
}

// Round 4
// 293.638 us; speedup vs baseline: 2.0265x; 1.1379x over previous
//
#include <hip/hip_runtime.h>
#include <math.h>

#define BNTOT 8192      // B*N
#define CH    64        // channels
#define KP1   11        // K+1 neighbors
#define NLOC  1568      // B * E  (8 * 196)
#define CAP   1024      // per-row global candidate capacity
#define LCAP  64        // per-row per-block LDS candidate capacity
#define MARGIN 2.5f     // bf16 score-error margin for the filter

typedef __attribute__((ext_vector_type(8))) short short8;   // 8 bf16 (4 VGPRs)
typedef __attribute__((ext_vector_type(4))) float float4v;  // MFMA C/D

// ---------- helpers ----------
__device__ __forceinline__ int pcnt(int p) {
  int lo = p - 4; if (lo < 0) lo = 0; lo += (lo & 1);
  int hi = p; if (hi > 26) hi = 26;
  return (hi >= lo) ? (((hi - lo) >> 1) + 1) : 0;
}
__device__ __forceinline__ float dv2_of(int u) {
  int node = u & 1023;
  int rr = node >> 5, cc = node & 31;
  int dv = KP1 + pcnt(rr) * pcnt(cc);
  return 1.0f / sqrtf((float)dv);
}
__device__ __forceinline__ unsigned short f2bf(float f) {   // RNE fp32->bf16
  unsigned u = __float_as_uint(f);
  unsigned r = (u + 0x7FFFu + ((u >> 16) & 1u)) >> 16;
  return (unsigned short)r;
}

// ---------- K0: cast to bf16 + row squared norms (fused) ----------
__global__ void k_cast(const float* __restrict__ X, unsigned short* __restrict__ Xh,
                       float* __restrict__ sq) {
  int g = blockIdx.x * 256 + threadIdx.x;
  int lane = threadIdx.x & 63;
  float v = X[g];
  Xh[g] = f2bf(v);
  float s = v * v;
  #pragma unroll
  for (int off = 32; off >= 1; off >>= 1) s += __shfl_xor(s, off, 64);
  if (lane == 0) sq[g >> 6] = s;
}

// ---------- KA1: partial per-row top-11 over a 128-sample chunk ----------
// grid 1024 = 128 row-groups x 8 chunks; block 256 = 4 waves.
// lane = row (64 rows/group); wave w handles samples (chunk*4+w)*32+s, s<32;
// sample -> column j = sample*8. Branchless sorted-insert, values only.
__global__ __launch_bounds__(256)
void k_thrpart(const float* __restrict__ X, const float* __restrict__ sq,
               float* __restrict__ part) {
  const int tid = threadIdx.x, wave = tid >> 6, lane = tid & 63;
  const int rg = blockIdx.x >> 3, chunk = blockIdx.x & 7;
  const int row = rg * 64 + lane;
  float xr[CH];
  {
    const float4* xp = (const float4*)(X + (size_t)row * CH);
    #pragma unroll
    for (int k = 0; k < CH / 4; ++k) {
      float4 v = xp[k];
      xr[4*k+0] = v.x; xr[4*k+1] = v.y; xr[4*k+2] = v.z; xr[4*k+3] = v.w;
    }
  }
  float tv[KP1];
  #pragma unroll
  for (int t = 0; t < KP1; ++t) tv[t] = INFINITY;

  for (int s = 0; s < 32; ++s) {
    int j = __builtin_amdgcn_readfirstlane(((chunk * 4 + wave) * 32 + s) * 8);
    const float* cp = X + (size_t)j * CH;
    float d0 = 0.f, d1 = 0.f, d2 = 0.f, d3 = 0.f;
    #pragma unroll
    for (int k = 0; k < CH / 4; ++k) {
      d0 = fmaf(xr[4*k+0], cp[4*k+0], d0);
      d1 = fmaf(xr[4*k+1], cp[4*k+1], d1);
      d2 = fmaf(xr[4*k+2], cp[4*k+2], d2);
      d3 = fmaf(xr[4*k+3], cp[4*k+3], d3);
    }
    float cv = fmaf(-2.0f, (d0 + d1) + (d2 + d3), sq[j]);
    #pragma unroll
    for (int t = 0; t < KP1; ++t) {
      float lo = fminf(tv[t], cv), hi = fmaxf(tv[t], cv);
      tv[t] = lo; cv = hi;
    }
  }
  __shared__ float ls[4][64][KP1];
  #pragma unroll
  for (int t = 0; t < KP1; ++t) ls[wave][lane][t] = tv[t];
  __syncthreads();
  if (tid < 64) {
    float v[KP1];
    #pragma unroll
    for (int t = 0; t < KP1; ++t) v[t] = ls[0][tid][t];
    #pragma unroll
    for (int w = 1; w < 4; ++w)
      #pragma unroll
      for (int t = 0; t < KP1; ++t) {
        float cv = ls[w][tid][t];
        #pragma unroll
        for (int s2 = 0; s2 < KP1; ++s2) {
          float lo = fminf(v[s2], cv), hi = fmaxf(v[s2], cv);
          v[s2] = lo; cv = hi;
        }
      }
    size_t base = ((size_t)blockIdx.x * 64 + tid) * KP1;
    #pragma unroll
    for (int t = 0; t < KP1; ++t) part[base + t] = v[t];
  }
}

// ---------- KA2: merge 8 chunk-partials -> per-row threshold ----------
// grid 128 x 64 thr; thread = row.
__global__ void k_thrmerge(const float* __restrict__ part, float* __restrict__ thr) {
  const int rg = blockIdx.x, lane = threadIdx.x;
  const int row = rg * 64 + lane;
  float v[KP1];
  {
    size_t b0 = ((size_t)(rg * 8) * 64 + lane) * KP1;
    #pragma unroll
    for (int t = 0; t < KP1; ++t) v[t] = part[b0 + t];
  }
  for (int c = 1; c < 8; ++c) {
    size_t b = ((size_t)(rg * 8 + c) * 64 + lane) * KP1;
    #pragma unroll
    for (int t = 0; t < KP1; ++t) {
      float cv = part[b + t];
      #pragma unroll
      for (int s2 = 0; s2 < KP1; ++s2) {
        float lo = fminf(v[s2], cv), hi = fmaxf(v[s2], cv);
        v[s2] = lo; cv = hi;
      }
    }
  }
  thr[row] = v[KP1 - 1] + MARGIN;
}

// ---------- KB: MFMA all-pairs scores + filter -> LDS compaction -> packed cand ----------
// grid 1024 = 64 row-tiles(128 rows) x 16 col-tiles(512 cols); block 256 = 4 waves.
__global__ __launch_bounds__(256, 2)
void k_filter(const unsigned short* __restrict__ Xh, const float* __restrict__ sq,
              const float* __restrict__ thr, int* __restrict__ cnt,
              unsigned short* __restrict__ cand) {
  __shared__ unsigned short lcand[128][LCAP + 2];   // +2 pad: conflict-free epilogue
  __shared__ int lcnt[128];
  __shared__ int lbase[128];

  const int tid = threadIdx.x, wave = tid >> 6, lane = tid & 63;
  const int m = lane & 15, q = lane >> 4;
  const int rowbase = (blockIdx.x >> 4) * 128;
  const int colbase = (blockIdx.x & 15) * 512 + wave * 128;

  if (tid < 128) lcnt[tid] = 0;

  // A fragments: 8 row-subtiles x 2 k-chunks
  short8 a[8][2];
  #pragma unroll
  for (int rt = 0; rt < 8; ++rt)
    #pragma unroll
    for (int kc = 0; kc < 2; ++kc)
      a[rt][kc] = *(const short8*)(Xh + (size_t)(rowbase + rt * 16 + m) * CH + kc * 32 + q * 8);

  float thrv[32];
  #pragma unroll
  for (int rt = 0; rt < 8; ++rt)
    #pragma unroll
    for (int r = 0; r < 4; ++r)
      thrv[rt * 4 + r] = thr[rowbase + rt * 16 + q * 4 + r];

  __syncthreads();

  const float4v cz = {0.f, 0.f, 0.f, 0.f};
  for (int sub = 0; sub < 8; ++sub) {
    const int coln = colbase + sub * 16 + m;
    const short8* bp = (const short8*)(Xh + (size_t)coln * CH + q * 8);
    short8 b0 = bp[0];
    short8 b1 = bp[4];               // +32 bf16
    float sqc = sq[coln];
    #pragma unroll
    for (int rt = 0; rt < 8; ++rt) {
      float4v c = __builtin_amdgcn_mfma_f32_16x16x32_bf16(a[rt][0], b0, cz, 0, 0, 0);
      c = __builtin_amdgcn_mfma_f32_16x16x32_bf16(a[rt][1], b1, c, 0, 0, 0);
      #pragma unroll
      for (int r = 0; r < 4; ++r) {
        float score = fmaf(-2.0f, c[r], sqc);
        if (score < thrv[rt * 4 + r]) {
          int rl = rt * 16 + q * 4 + r;
          int s = atomicAdd(&lcnt[rl], 1);
          if (s < LCAP) {
            lcand[rl][s] = (unsigned short)coln;
          } else {                                   // rare overflow: direct global
            int gs = atomicAdd(&cnt[rowbase + rl], 1);
            if (gs < CAP) cand[(size_t)(rowbase + rl) * CAP + gs] = (unsigned short)coln;
          }
        }
      }
    }
  }

  __syncthreads();
  if (tid < 128) {
    int nl = lcnt[tid]; if (nl > LCAP) nl = LCAP;
    lbase[tid] = atomicAdd(&cnt[rowbase + tid], nl);
    lcnt[tid] = nl;
  }
  __syncthreads();
  if (tid < 128) {
    int nl = lcnt[tid], base = lbase[tid];
    unsigned short* dst = cand + (size_t)(rowbase + tid) * CAP;
    for (int s = 0; s < nl; ++s) {
      int g = base + s;
      if (g < CAP) dst[g] = lcand[tid][s];
    }
  }
}

// ---------- KC: exact fp32 rescore of candidates + top-11 + DE ----------
// 512 blocks x 256 thr; 16 rows/block, 16 lanes/row.
__global__ __launch_bounds__(256)
void k_rescore(const float* __restrict__ X, const float* __restrict__ sq,
               const int* __restrict__ cnt, const unsigned short* __restrict__ cand,
               int* __restrict__ inds, int* __restrict__ DE) {
  const int tid = threadIdx.x, wave = tid >> 6, lane = tid & 63;
  const int ph = lane & 15, rl = lane >> 4;
  const int row = blockIdx.x * 16 + wave * 4 + rl;

  float xr[CH];
  {
    const float4* xp = (const float4*)(X + (size_t)row * CH);
    #pragma unroll
    for (int k = 0; k < CH / 4; ++k) {
      float4 v = xp[k];
      xr[4*k+0] = v.x; xr[4*k+1] = v.y; xr[4*k+2] = v.z; xr[4*k+3] = v.w;
    }
  }
  int n = cnt[row]; if (n > CAP) n = CAP;

  float tv[KP1]; int ti[KP1];
  #pragma unroll
  for (int t = 0; t < KP1; ++t) { tv[t] = INFINITY; ti[t] = -1; }

  for (int s = ph; s < n; s += 16) {
    int cj = cand[(size_t)row * CAP + s];
    const float4* cp = (const float4*)(X + (size_t)cj * CH);
    float d0 = 0.f, d1 = 0.f, d2 = 0.f, d3 = 0.f;
    #pragma unroll
    for (int k = 0; k < CH / 4; ++k) {
      float4 v = cp[k];
      d0 = fmaf(xr[4*k+0], v.x, d0);
      d1 = fmaf(xr[4*k+1], v.y, d1);
      d2 = fmaf(xr[4*k+2], v.z, d2);
      d3 = fmaf(xr[4*k+3], v.w, d3);
    }
    float score = fmaf(-2.0f, (d0 + d1) + (d2 + d3), sq[cj]);
    if (score < tv[KP1 - 1]) {
      float cv = score; int ci = cj;
      #pragma unroll
      for (int t = 0; t < KP1; ++t) {
        bool sw = cv < tv[t];
        float nv = sw ? cv   : tv[t]; int ni = sw ? ci   : ti[t];
        float ov = sw ? tv[t] : cv;   int oi = sw ? ti[t] : ci;
        tv[t] = nv; ti[t] = ni; cv = ov; ci = oi;
      }
    }
  }
  __shared__ float lv[256][KP1];
  __shared__ int   li[256][KP1];
  #pragma unroll
  for (int t = 0; t < KP1; ++t) { lv[tid][t] = tv[t]; li[tid][t] = ti[t]; }
  __syncthreads();
  if (tid < 16) {
    const int r = tid;
    const int base = (r >> 2) * 64 + (r & 3) * 16;   // wave*64 + rl*16
    float v[KP1]; int id[KP1];
    #pragma unroll
    for (int t = 0; t < KP1; ++t) { v[t] = lv[base][t]; id[t] = li[base][t]; }
    for (int j = 1; j < 16; ++j) {
      #pragma unroll
      for (int t = 0; t < KP1; ++t) {
        float cv = lv[base + j][t]; int ci = li[base + j][t];
        if (cv < v[KP1 - 1]) {
          #pragma unroll
          for (int s2 = 0; s2 < KP1; ++s2) {
            bool sw = cv < v[s2];
            float nv = sw ? cv    : v[s2]; int ni = sw ? ci     : id[s2];
            float ov = sw ? v[s2] : cv;    int oi = sw ? id[s2] : ci;
            v[s2] = nv; id[s2] = ni; cv = ov; ci = oi;
          }
        }
      }
    }
    int orow = blockIdx.x * 16 + r;
    #pragma unroll
    for (int t = 0; t < KP1; ++t) {
      inds[orow * KP1 + t] = id[t];
      atomicAdd(&DE[id[t]], 1);
    }
  }
}

// ---------- K3: t = Dv^{-1/2} * (x @ W^T + b) ----------
__global__ void k_lin(const float* __restrict__ X, const float* __restrict__ W,
                      const float* __restrict__ bias, float* __restrict__ t) {
  int lane = threadIdx.x & 63;
  int wave = threadIdx.x >> 6;
  int rowbase = (blockIdx.x * 4 + wave) * 16;
  float wr[CH];
  {
    const float4* wp = (const float4*)(W + (size_t)lane * CH);
    #pragma unroll
    for (int k = 0; k < CH / 4; ++k) {
      float4 v = wp[k];
      wr[4*k+0] = v.x; wr[4*k+1] = v.y; wr[4*k+2] = v.z; wr[4*k+3] = v.w;
    }
  }
  float bc = bias[lane];
  for (int r = 0; r < 16; ++r) {
    int row = __builtin_amdgcn_readfirstlane(rowbase + r);
    const float* xp = X + (size_t)row * CH;
    float d0 = 0.f, d1 = 0.f, d2 = 0.f, d3 = 0.f;
    #pragma unroll
    for (int k = 0; k < CH / 4; ++k) {
      d0 = fmaf(wr[4*k+0], xp[4*k+0], d0);
      d1 = fmaf(wr[4*k+1], xp[4*k+1], d1);
      d2 = fmaf(wr[4*k+2], xp[4*k+2], d2);
      d3 = fmaf(wr[4*k+3], xp[4*k+3], d3);
    }
    float y = (d0 + d1) + (d2 + d3) + bc;
    t[(size_t)row * CH + lane] = y * dv2_of(row);
  }
}

// ---------- K4a: scatter t into KNN edge sums ----------
__global__ void k_scatter(const float* __restrict__ t, const int* __restrict__ inds,
                          float* __restrict__ s_knn) {
  int c = threadIdx.x & 63;
  int u = blockIdx.x * 4 + (threadIdx.x >> 6);
  float val = t[(size_t)u * CH + c];
  int ub = __builtin_amdgcn_readfirstlane(u);
  const int* ip = inds + (size_t)ub * KP1;
  #pragma unroll
  for (int j = 0; j < KP1; ++j) {
    int e = ip[j];
    atomicAdd(&s_knn[(size_t)e * CH + c], val);
  }
}

// ---------- K4b: local patch edge sums, pre-scaled by 1/De (=1/25) ----------
__global__ void k_local(const float* __restrict__ t, float* __restrict__ s_loc) {
  int c = threadIdx.x & 63;
  int e = blockIdx.x * 4 + (threadIdx.x >> 6);
  int b  = e / 196;
  int le = e - b * 196;
  int pi = le / 14;
  int pj = le - pi * 14;
  int base = b * 1024 + (pi * 2) * 32 + pj * 2;
  float acc = 0.f;
  #pragma unroll
  for (int di = 0; di < 5; ++di)
    #pragma unroll
    for (int dj = 0; dj < 5; ++dj)
      acc += t[(size_t)(base + di * 32 + dj) * CH + c];
  s_loc[(size_t)e * CH + c] = acc * (1.0f / 25.0f);
}

// ---------- K5: z[u] = dv2_u * ( sum_knn s_knn[e]/DE[e] + sum_local s_loc[p] ) ----------
__global__ void k_gather(const float* __restrict__ s_knn, const float* __restrict__ s_loc,
                         const int* __restrict__ inds, const int* __restrict__ DE,
                         float* __restrict__ z) {
  int c = threadIdx.x & 63;
  int u = blockIdx.x * 4 + (threadIdx.x >> 6);
  int ub = __builtin_amdgcn_readfirstlane(u);
  const int* ip = inds + (size_t)ub * KP1;
  float acc = 0.f;
  #pragma unroll
  for (int j = 0; j < KP1; ++j) {
    int e = ip[j];
    float invde = 1.0f / (float)DE[e];
    acc += s_knn[(size_t)e * CH + c] * invde;
  }
  int node = ub & 1023, b = ub >> 10;
  int rr = node >> 5, cc = node & 31;
  int i0 = rr - 4; if (i0 < 0) i0 = 0; i0 += (i0 & 1);
  int i1 = rr; if (i1 > 26) i1 = 26;
  int j0 = cc - 4; if (j0 < 0) j0 = 0; j0 += (j0 & 1);
  int j1 = cc; if (j1 > 26) j1 = 26;
  for (int i = i0; i <= i1; i += 2)
    for (int jj = j0; jj <= j1; jj += 2) {
      int e = b * 196 + (i >> 1) * 14 + (jj >> 1);
      acc += s_loc[(size_t)e * CH + c];
    }
  z[(size_t)ub * CH + c] = acc * dv2_of(ub);
}

// ---------- K6a: per-64-row-block partial BN sums ----------
__global__ void k_bnpart(const float* __restrict__ z, float* __restrict__ part,
                         float* __restrict__ partsq) {
  int c = threadIdx.x & 63;
  int rq = threadIdx.x >> 6;
  int blk = blockIdx.x;
  float s = 0.f, s2 = 0.f;
  for (int k = 0; k < 16; ++k) {
    float v = z[(size_t)(blk * 64 + rq * 16 + k) * CH + c];
    s += v; s2 += v * v;
  }
  __shared__ float ls[4][CH], ls2[4][CH];
  ls[rq][c] = s; ls2[rq][c] = s2;
  __syncthreads();
  if (rq == 0) {
    part[(size_t)blk * CH + c]   = ls[0][c] + ls[1][c] + ls[2][c] + ls[3][c];
    partsq[(size_t)blk * CH + c] = ls2[0][c] + ls2[1][c] + ls2[2][c] + ls2[3][c];
  }
}

// ---------- K6b: finalize mu / rstd ----------
__global__ void k_bnfin(const float* __restrict__ part, const float* __restrict__ partsq,
                        float* __restrict__ mu, float* __restrict__ rstd) {
  int c = threadIdx.x;
  float s = 0.f, s2 = 0.f;
  for (int b = 0; b < 128; ++b) { s += part[(size_t)b * CH + c]; s2 += partsq[(size_t)b * CH + c]; }
  float m = s * (1.0f / (float)BNTOT);
  float var = s2 * (1.0f / (float)BNTOT) - m * m;
  mu[c] = m;
  rstd[c] = 1.0f / sqrtf(var + 1e-5f);
}

// ---------- K7: BN apply + relu + residual ----------
__global__ void k_out(const float* __restrict__ z, const float* __restrict__ X,
                      const float* __restrict__ mu, const float* __restrict__ rstd,
                      const float* __restrict__ gamma, const float* __restrict__ beta,
                      float* __restrict__ out) {
  int c = threadIdx.x & 63;
  int u = blockIdx.x * 4 + (threadIdx.x >> 6);
  size_t idx = (size_t)u * CH + c;
  float zn = (z[idx] - mu[c]) * rstd[c] * gamma[c] + beta[c];
  out[idx] = fmaxf(zn, 0.f) + X[idx];
}

// ---------- launch ----------
extern "C" void kernel_launch(void* const* d_in, const int* in_sizes, int n_in,
                              void* d_out, int out_size, void* d_ws, size_t ws_size,
                              hipStream_t stream) {
  const float* X     = (const float*)d_in[0];
  const float* W     = (const float*)d_in[1];
  const float* bias  = (const float*)d_in[2];
  const float* gamma = (const float*)d_in[3];
  const float* beta  = (const float*)d_in[4];
  float* out = (float*)d_out;

  // workspace layout
  float* ws = (float*)d_ws;
  float* sq      = ws;                       // 8192
  float* thr     = sq + 8192;                // 8192
  float* t       = thr + 8192;               // 524288
  float* s_loc   = t + 524288;               // 100352
  float* z       = s_loc + 100352;           // 524288
  float* part    = z + 524288;               // 8192
  float* partsq  = part + 8192;              // 8192
  float* mu      = partsq + 8192;            // 64
  float* rstd    = mu + 64;                  // 64
  float* thrpart = rstd + 64;                // 1024*64*11 = 720896
  int*   inds    = (int*)(thrpart + 720896); // 90112 ints
  unsigned short* Xh   = (unsigned short*)(inds + 90112);   // 524288 shorts
  unsigned short* cand = Xh + 524288;                        // 8192*1024 shorts
  // zeroed region: cnt (8192 int) + DE (8192 int) + s_knn (524288 f), contiguous
  int*   cnt    = (int*)(cand + (size_t)8192 * CAP);
  int*   DE     = cnt + 8192;
  float* s_knn  = (float*)(DE + 8192);

  hipMemsetAsync(cnt, 0, (size_t)(8192 + 8192 + 524288) * 4, stream);

  k_cast    <<<2048, 256, 0, stream>>>(X, Xh, sq);
  k_thrpart <<<1024, 256, 0, stream>>>(X, sq, thrpart);
  k_thrmerge<<<128, 64, 0, stream>>>(thrpart, thr);
  k_filter  <<<1024, 256, 0, stream>>>(Xh, sq, thr, cnt, cand);
  k_rescore <<<512, 256, 0, stream>>>(X, sq, cnt, cand, inds, DE);
  k_lin     <<<128, 256, 0, stream>>>(X, W, bias, t);
  k_scatter <<<BNTOT / 4, 256, 0, stream>>>(t, inds, s_knn);
  k_local   <<<NLOC / 4, 256, 0, stream>>>(t, s_loc);
  k_gather  <<<BNTOT / 4, 256, 0, stream>>>(s_knn, s_loc, inds, DE, z);
  k_bnpart  <<<128, 256, 0, stream>>>(z, part, partsq);
  k_bnfin   <<<1, 64, 0, stream>>>(part, partsq, mu, rstd);
  k_out     <<<BNTOT / 4, 256, 0, stream>>>(z, X, mu, rstd, gamma, beta, out);

  (void)in_sizes; (void)n_in; (void)out_size; (void)ws_size;
}

// Round 5
// 266.959 us; speedup vs baseline: 2.2290x; 1.0999x over previous
//
#include <hip/hip_runtime.h>
#include <math.h>

#define BNTOT 8192      // B*N
#define CH    64        // channels
#define KP1   11        // K+1 neighbors
#define NLOC  1568      // B * E  (8 * 196)
#define CAP   1024      // per-row global candidate capacity
#define LCAP  64        // per-row per-block LDS candidate capacity
#define MARGIN 2.5f     // bf16 score-error margin for the filter

typedef __attribute__((ext_vector_type(8))) short short8;   // 8 bf16 (4 VGPRs)
typedef __attribute__((ext_vector_type(4))) float float4v;  // MFMA C/D

// ---------- helpers ----------
__device__ __forceinline__ int pcnt(int p) {
  int lo = p - 4; if (lo < 0) lo = 0; lo += (lo & 1);
  int hi = p; if (hi > 26) hi = 26;
  return (hi >= lo) ? (((hi - lo) >> 1) + 1) : 0;
}
__device__ __forceinline__ float dv2_of(int u) {
  int node = u & 1023;
  int rr = node >> 5, cc = node & 31;
  int dv = KP1 + pcnt(rr) * pcnt(cc);
  return 1.0f / sqrtf((float)dv);
}
__device__ __forceinline__ unsigned short f2bf(float f) {   // RNE fp32->bf16
  unsigned u = __float_as_uint(f);
  unsigned r = (u + 0x7FFFu + ((u >> 16) & 1u)) >> 16;
  return (unsigned short)r;
}
// monotone key: flip fp32 bits so unsigned compare == float compare
__device__ __forceinline__ unsigned long long skey(float s, int idx) {
  unsigned u = __float_as_uint(s);
  u = (u & 0x80000000u) ? ~u : (u | 0x80000000u);
  return ((unsigned long long)u << 32) | (unsigned)idx;
}

// ---------- K0: cast to bf16 + row squared norms (fused) ----------
__global__ void k_cast(const float* __restrict__ X, unsigned short* __restrict__ Xh,
                       float* __restrict__ sq) {
  int g = blockIdx.x * 256 + threadIdx.x;
  int lane = threadIdx.x & 63;
  float v = X[g];
  Xh[g] = f2bf(v);
  float s = v * v;
  #pragma unroll
  for (int off = 32; off >= 1; off >>= 1) s += __shfl_xor(s, off, 64);
  if (lane == 0) sq[g >> 6] = s;
}

// ---------- KA1: partial per-row top-11 over a 128-sample chunk ----------
// grid 1024 = 128 row-groups x 8 chunks; block 256 = 4 waves.
__global__ __launch_bounds__(256)
void k_thrpart(const float* __restrict__ X, const float* __restrict__ sq,
               float* __restrict__ part) {
  const int tid = threadIdx.x, wave = tid >> 6, lane = tid & 63;
  const int rg = blockIdx.x >> 3, chunk = blockIdx.x & 7;
  const int row = rg * 64 + lane;
  float xr[CH];
  {
    const float4* xp = (const float4*)(X + (size_t)row * CH);
    #pragma unroll
    for (int k = 0; k < CH / 4; ++k) {
      float4 v = xp[k];
      xr[4*k+0] = v.x; xr[4*k+1] = v.y; xr[4*k+2] = v.z; xr[4*k+3] = v.w;
    }
  }
  float tv[KP1];
  #pragma unroll
  for (int t = 0; t < KP1; ++t) tv[t] = INFINITY;

  for (int s = 0; s < 32; ++s) {
    int j = __builtin_amdgcn_readfirstlane(((chunk * 4 + wave) * 32 + s) * 8);
    const float* cp = X + (size_t)j * CH;
    float d0 = 0.f, d1 = 0.f, d2 = 0.f, d3 = 0.f;
    #pragma unroll
    for (int k = 0; k < CH / 4; ++k) {
      d0 = fmaf(xr[4*k+0], cp[4*k+0], d0);
      d1 = fmaf(xr[4*k+1], cp[4*k+1], d1);
      d2 = fmaf(xr[4*k+2], cp[4*k+2], d2);
      d3 = fmaf(xr[4*k+3], cp[4*k+3], d3);
    }
    float cv = fmaf(-2.0f, (d0 + d1) + (d2 + d3), sq[j]);
    #pragma unroll
    for (int t = 0; t < KP1; ++t) {
      float lo = fminf(tv[t], cv), hi = fmaxf(tv[t], cv);
      tv[t] = lo; cv = hi;
    }
  }
  __shared__ float ls[4][64][KP1];
  #pragma unroll
  for (int t = 0; t < KP1; ++t) ls[wave][lane][t] = tv[t];
  __syncthreads();
  if (tid < 64) {
    float v[KP1];
    #pragma unroll
    for (int t = 0; t < KP1; ++t) v[t] = ls[0][tid][t];
    #pragma unroll
    for (int w = 1; w < 4; ++w)
      #pragma unroll
      for (int t = 0; t < KP1; ++t) {
        float cv = ls[w][tid][t];
        #pragma unroll
        for (int s2 = 0; s2 < KP1; ++s2) {
          float lo = fminf(v[s2], cv), hi = fmaxf(v[s2], cv);
          v[s2] = lo; cv = hi;
        }
      }
    size_t base = ((size_t)blockIdx.x * 64 + tid) * KP1;
    #pragma unroll
    for (int t = 0; t < KP1; ++t) part[base + t] = v[t];
  }
}

// ---------- KA2: merge 8 chunk-partials -> per-row threshold ----------
__global__ void k_thrmerge(const float* __restrict__ part, float* __restrict__ thr) {
  const int rg = blockIdx.x, lane = threadIdx.x;
  const int row = rg * 64 + lane;
  float v[KP1];
  {
    size_t b0 = ((size_t)(rg * 8) * 64 + lane) * KP1;
    #pragma unroll
    for (int t = 0; t < KP1; ++t) v[t] = part[b0 + t];
  }
  for (int c = 1; c < 8; ++c) {
    size_t b = ((size_t)(rg * 8 + c) * 64 + lane) * KP1;
    #pragma unroll
    for (int t = 0; t < KP1; ++t) {
      float cv = part[b + t];
      #pragma unroll
      for (int s2 = 0; s2 < KP1; ++s2) {
        float lo = fminf(v[s2], cv), hi = fmaxf(v[s2], cv);
        v[s2] = lo; cv = hi;
      }
    }
  }
  thr[row] = v[KP1 - 1] + MARGIN;
}

// ---------- KB: MFMA all-pairs scores + filter -> LDS compaction -> packed cand ----------
// grid 1024 = 64 row-tiles(128 rows) x 16 col-tiles(512 cols); block 256 = 4 waves.
__global__ __launch_bounds__(256, 2)
void k_filter(const unsigned short* __restrict__ Xh, const float* __restrict__ sq,
              const float* __restrict__ thr, int* __restrict__ cnt,
              unsigned short* __restrict__ cand) {
  __shared__ unsigned short lcand[128][LCAP + 2];   // +2 pad: conflict-free epilogue
  __shared__ int lcnt[128];
  __shared__ int lbase[128];

  const int tid = threadIdx.x, wave = tid >> 6, lane = tid & 63;
  const int m = lane & 15, q = lane >> 4;
  const int rowbase = (blockIdx.x >> 4) * 128;
  const int colbase = (blockIdx.x & 15) * 512 + wave * 128;

  if (tid < 128) lcnt[tid] = 0;

  short8 a[8][2];
  #pragma unroll
  for (int rt = 0; rt < 8; ++rt)
    #pragma unroll
    for (int kc = 0; kc < 2; ++kc)
      a[rt][kc] = *(const short8*)(Xh + (size_t)(rowbase + rt * 16 + m) * CH + kc * 32 + q * 8);

  float thrv[32];
  #pragma unroll
  for (int rt = 0; rt < 8; ++rt)
    #pragma unroll
    for (int r = 0; r < 4; ++r)
      thrv[rt * 4 + r] = thr[rowbase + rt * 16 + q * 4 + r];

  __syncthreads();

  const float4v cz = {0.f, 0.f, 0.f, 0.f};
  for (int sub = 0; sub < 8; ++sub) {
    const int coln = colbase + sub * 16 + m;
    const short8* bp = (const short8*)(Xh + (size_t)coln * CH + q * 8);
    short8 b0 = bp[0];
    short8 b1 = bp[4];               // +32 bf16
    float sqc = sq[coln];
    #pragma unroll
    for (int rt = 0; rt < 8; ++rt) {
      float4v c = __builtin_amdgcn_mfma_f32_16x16x32_bf16(a[rt][0], b0, cz, 0, 0, 0);
      c = __builtin_amdgcn_mfma_f32_16x16x32_bf16(a[rt][1], b1, c, 0, 0, 0);
      #pragma unroll
      for (int r = 0; r < 4; ++r) {
        float score = fmaf(-2.0f, c[r], sqc);
        if (score < thrv[rt * 4 + r]) {
          int rl = rt * 16 + q * 4 + r;
          int s = atomicAdd(&lcnt[rl], 1);
          if (s < LCAP) {
            lcand[rl][s] = (unsigned short)coln;
          } else {                                   // rare overflow: direct global
            int gs = atomicAdd(&cnt[rowbase + rl], 1);
            if (gs < CAP) cand[(size_t)(rowbase + rl) * CAP + gs] = (unsigned short)coln;
          }
        }
      }
    }
  }

  __syncthreads();
  if (tid < 128) {
    int nl = lcnt[tid]; if (nl > LCAP) nl = LCAP;
    lbase[tid] = atomicAdd(&cnt[rowbase + tid], nl);
    lcnt[tid] = nl;
  }
  __syncthreads();
  if (tid < 128) {
    int nl = lcnt[tid], base = lbase[tid];
    unsigned short* dst = cand + (size_t)(rowbase + tid) * CAP;
    for (int s = 0; s < nl; ++s) {
      int g = base + s;
      if (g < CAP) dst[g] = lcand[tid][s];
    }
  }
}

// ---------- KC: exact fp32 rescore, one wave per row, no LDS ----------
// grid 2048 x 256 thr; 4 rows/block (one wave each), 64 lanes split candidates.
// Phase 1: per-lane gather-dot + guarded insert into sorted-11.
// Phase 2: 11x wave-min extraction on packed u64 (score|idx) keys.
__global__ __launch_bounds__(256)
void k_rescore(const float* __restrict__ X, const float* __restrict__ sq,
               const int* __restrict__ cnt, const unsigned short* __restrict__ cand,
               int* __restrict__ inds, int* __restrict__ DE) {
  const int tid = threadIdx.x, lane = tid & 63;
  const int row = __builtin_amdgcn_readfirstlane(blockIdx.x * 4 + (tid >> 6));

  // own row (wave-uniform address)
  float xr[CH];
  {
    const float4* xp = (const float4*)(X + (size_t)row * CH);
    #pragma unroll
    for (int k = 0; k < CH / 4; ++k) {
      float4 v = xp[k];
      xr[4*k+0] = v.x; xr[4*k+1] = v.y; xr[4*k+2] = v.z; xr[4*k+3] = v.w;
    }
  }
  int n = cnt[row]; if (n > CAP) n = CAP;

  float tv[KP1]; int ti[KP1];
  #pragma unroll
  for (int t = 0; t < KP1; ++t) { tv[t] = INFINITY; ti[t] = -1; }

  for (int s = lane; s < n; s += 64) {
    int cj = cand[(size_t)row * CAP + s];
    const float4* cp = (const float4*)(X + (size_t)cj * CH);
    float d0 = 0.f, d1 = 0.f, d2 = 0.f, d3 = 0.f;
    #pragma unroll
    for (int k = 0; k < CH / 4; ++k) {
      float4 v = cp[k];
      d0 = fmaf(xr[4*k+0], v.x, d0);
      d1 = fmaf(xr[4*k+1], v.y, d1);
      d2 = fmaf(xr[4*k+2], v.z, d2);
      d3 = fmaf(xr[4*k+3], v.w, d3);
    }
    float score = fmaf(-2.0f, (d0 + d1) + (d2 + d3), sq[cj]);
    if (score < tv[KP1 - 1]) {
      float cv = score; int ci = cj;
      #pragma unroll
      for (int t = 0; t < KP1; ++t) {
        bool sw = cv < tv[t];
        float nv = sw ? cv   : tv[t]; int ni = sw ? ci   : ti[t];
        float ov = sw ? tv[t] : cv;   int oi = sw ? ti[t] : ci;
        tv[t] = nv; ti[t] = ni; cv = ov; ci = oi;
      }
    }
  }

  // 11 wave-min extractions; idx unique per row -> unique winner each time
  unsigned long long cur = skey(tv[0], ti[0]);
  unsigned long long keep = 0;
  #pragma unroll
  for (int t = 0; t < KP1; ++t) {
    unsigned long long m = cur;
    #pragma unroll
    for (int off = 1; off < 64; off <<= 1) {
      unsigned lo = __shfl_xor((unsigned)m, off, 64);
      unsigned hi = __shfl_xor((unsigned)(m >> 32), off, 64);
      unsigned long long o = ((unsigned long long)hi << 32) | lo;
      m = (o < m) ? o : m;
    }
    if (lane == t) keep = m;
    if (cur == m) {                      // winner pops its front
      #pragma unroll
      for (int q = 0; q < KP1 - 1; ++q) { tv[q] = tv[q+1]; ti[q] = ti[q+1]; }
      tv[KP1-1] = INFINITY; ti[KP1-1] = -1;
      cur = skey(tv[0], ti[0]);
    }
  }
  if (lane < KP1) {
    int idx = (int)(unsigned)(keep & 0xFFFFFFFFu);
    inds[(size_t)row * KP1 + lane] = idx;
    atomicAdd(&DE[idx], 1);
  }
}

// ---------- K3: t = Dv^{-1/2} * (x @ W^T + b) ----------
__global__ void k_lin(const float* __restrict__ X, const float* __restrict__ W,
                      const float* __restrict__ bias, float* __restrict__ t) {
  int lane = threadIdx.x & 63;
  int wave = threadIdx.x >> 6;
  int rowbase = (blockIdx.x * 4 + wave) * 16;
  float wr[CH];
  {
    const float4* wp = (const float4*)(W + (size_t)lane * CH);
    #pragma unroll
    for (int k = 0; k < CH / 4; ++k) {
      float4 v = wp[k];
      wr[4*k+0] = v.x; wr[4*k+1] = v.y; wr[4*k+2] = v.z; wr[4*k+3] = v.w;
    }
  }
  float bc = bias[lane];
  for (int r = 0; r < 16; ++r) {
    int row = __builtin_amdgcn_readfirstlane(rowbase + r);
    const float* xp = X + (size_t)row * CH;
    float d0 = 0.f, d1 = 0.f, d2 = 0.f, d3 = 0.f;
    #pragma unroll
    for (int k = 0; k < CH / 4; ++k) {
      d0 = fmaf(wr[4*k+0], xp[4*k+0], d0);
      d1 = fmaf(wr[4*k+1], xp[4*k+1], d1);
      d2 = fmaf(wr[4*k+2], xp[4*k+2], d2);
      d3 = fmaf(wr[4*k+3], xp[4*k+3], d3);
    }
    float y = (d0 + d1) + (d2 + d3) + bc;
    t[(size_t)row * CH + lane] = y * dv2_of(row);
  }
}

// ---------- K4a: scatter t into KNN edge sums ----------
__global__ void k_scatter(const float* __restrict__ t, const int* __restrict__ inds,
                          float* __restrict__ s_knn) {
  int c = threadIdx.x & 63;
  int u = blockIdx.x * 4 + (threadIdx.x >> 6);
  float val = t[(size_t)u * CH + c];
  int ub = __builtin_amdgcn_readfirstlane(u);
  const int* ip = inds + (size_t)ub * KP1;
  #pragma unroll
  for (int j = 0; j < KP1; ++j) {
    int e = ip[j];
    atomicAdd(&s_knn[(size_t)e * CH + c], val);
  }
}

// ---------- K4b: local patch edge sums, pre-scaled by 1/De (=1/25) ----------
__global__ void k_local(const float* __restrict__ t, float* __restrict__ s_loc) {
  int c = threadIdx.x & 63;
  int e = blockIdx.x * 4 + (threadIdx.x >> 6);
  int b  = e / 196;
  int le = e - b * 196;
  int pi = le / 14;
  int pj = le - pi * 14;
  int base = b * 1024 + (pi * 2) * 32 + pj * 2;
  float acc = 0.f;
  #pragma unroll
  for (int di = 0; di < 5; ++di)
    #pragma unroll
    for (int dj = 0; dj < 5; ++dj)
      acc += t[(size_t)(base + di * 32 + dj) * CH + c];
  s_loc[(size_t)e * CH + c] = acc * (1.0f / 25.0f);
}

// ---------- K5: z[u] = dv2_u * ( sum_knn s_knn[e]/DE[e] + sum_local s_loc[p] ) ----------
__global__ void k_gather(const float* __restrict__ s_knn, const float* __restrict__ s_loc,
                         const int* __restrict__ inds, const int* __restrict__ DE,
                         float* __restrict__ z) {
  int c = threadIdx.x & 63;
  int u = blockIdx.x * 4 + (threadIdx.x >> 6);
  int ub = __builtin_amdgcn_readfirstlane(u);
  const int* ip = inds + (size_t)ub * KP1;
  float acc = 0.f;
  #pragma unroll
  for (int j = 0; j < KP1; ++j) {
    int e = ip[j];
    float invde = 1.0f / (float)DE[e];
    acc += s_knn[(size_t)e * CH + c] * invde;
  }
  int node = ub & 1023, b = ub >> 10;
  int rr = node >> 5, cc = node & 31;
  int i0 = rr - 4; if (i0 < 0) i0 = 0; i0 += (i0 & 1);
  int i1 = rr; if (i1 > 26) i1 = 26;
  int j0 = cc - 4; if (j0 < 0) j0 = 0; j0 += (j0 & 1);
  int j1 = cc; if (j1 > 26) j1 = 26;
  for (int i = i0; i <= i1; i += 2)
    for (int jj = j0; jj <= j1; jj += 2) {
      int e = b * 196 + (i >> 1) * 14 + (jj >> 1);
      acc += s_loc[(size_t)e * CH + c];
    }
  z[(size_t)ub * CH + c] = acc * dv2_of(ub);
}

// ---------- K6a: per-64-row-block partial BN sums ----------
__global__ void k_bnpart(const float* __restrict__ z, float* __restrict__ part,
                         float* __restrict__ partsq) {
  int c = threadIdx.x & 63;
  int rq = threadIdx.x >> 6;
  int blk = blockIdx.x;
  float s = 0.f, s2 = 0.f;
  for (int k = 0; k < 16; ++k) {
    float v = z[(size_t)(blk * 64 + rq * 16 + k) * CH + c];
    s += v; s2 += v * v;
  }
  __shared__ float ls[4][CH], ls2[4][CH];
  ls[rq][c] = s; ls2[rq][c] = s2;
  __syncthreads();
  if (rq == 0) {
    part[(size_t)blk * CH + c]   = ls[0][c] + ls[1][c] + ls[2][c] + ls[3][c];
    partsq[(size_t)blk * CH + c] = ls2[0][c] + ls2[1][c] + ls2[2][c] + ls2[3][c];
  }
}

// ---------- K6b: finalize mu / rstd ----------
__global__ void k_bnfin(const float* __restrict__ part, const float* __restrict__ partsq,
                        float* __restrict__ mu, float* __restrict__ rstd) {
  int c = threadIdx.x;
  float s = 0.f, s2 = 0.f;
  for (int b = 0; b < 128; ++b) { s += part[(size_t)b * CH + c]; s2 += partsq[(size_t)b * CH + c]; }
  float m = s * (1.0f / (float)BNTOT);
  float var = s2 * (1.0f / (float)BNTOT) - m * m;
  mu[c] = m;
  rstd[c] = 1.0f / sqrtf(var + 1e-5f);
}

// ---------- K7: BN apply + relu + residual ----------
__global__ void k_out(const float* __restrict__ z, const float* __restrict__ X,
                      const float* __restrict__ mu, const float* __restrict__ rstd,
                      const float* __restrict__ gamma, const float* __restrict__ beta,
                      float* __restrict__ out) {
  int c = threadIdx.x & 63;
  int u = blockIdx.x * 4 + (threadIdx.x >> 6);
  size_t idx = (size_t)u * CH + c;
  float zn = (z[idx] - mu[c]) * rstd[c] * gamma[c] + beta[c];
  out[idx] = fmaxf(zn, 0.f) + X[idx];
}

// ---------- launch ----------
extern "C" void kernel_launch(void* const* d_in, const int* in_sizes, int n_in,
                              void* d_out, int out_size, void* d_ws, size_t ws_size,
                              hipStream_t stream) {
  const float* X     = (const float*)d_in[0];
  const float* W     = (const float*)d_in[1];
  const float* bias  = (const float*)d_in[2];
  const float* gamma = (const float*)d_in[3];
  const float* beta  = (const float*)d_in[4];
  float* out = (float*)d_out;

  // workspace layout
  float* ws = (float*)d_ws;
  float* sq      = ws;                       // 8192
  float* thr     = sq + 8192;                // 8192
  float* t       = thr + 8192;               // 524288
  float* s_loc   = t + 524288;               // 100352
  float* z       = s_loc + 100352;           // 524288
  float* part    = z + 524288;               // 8192
  float* partsq  = part + 8192;              // 8192
  float* mu      = partsq + 8192;            // 64
  float* rstd    = mu + 64;                  // 64
  float* thrpart = rstd + 64;                // 1024*64*11 = 720896
  int*   inds    = (int*)(thrpart + 720896); // 90112 ints
  unsigned short* Xh   = (unsigned short*)(inds + 90112);   // 524288 shorts
  unsigned short* cand = Xh + 524288;                        // 8192*1024 shorts
  // zeroed region: cnt (8192 int) + DE (8192 int) + s_knn (524288 f), contiguous
  int*   cnt    = (int*)(cand + (size_t)8192 * CAP);
  int*   DE     = cnt + 8192;
  float* s_knn  = (float*)(DE + 8192);

  hipMemsetAsync(cnt, 0, (size_t)(8192 + 8192 + 524288) * 4, stream);

  k_cast    <<<2048, 256, 0, stream>>>(X, Xh, sq);
  k_thrpart <<<1024, 256, 0, stream>>>(X, sq, thrpart);
  k_thrmerge<<<128, 64, 0, stream>>>(thrpart, thr);
  k_filter  <<<1024, 256, 0, stream>>>(Xh, sq, thr, cnt, cand);
  k_rescore <<<2048, 256, 0, stream>>>(X, sq, cnt, cand, inds, DE);
  k_lin     <<<128, 256, 0, stream>>>(X, W, bias, t);
  k_scatter <<<BNTOT / 4, 256, 0, stream>>>(t, inds, s_knn);
  k_local   <<<NLOC / 4, 256, 0, stream>>>(t, s_loc);
  k_gather  <<<BNTOT / 4, 256, 0, stream>>>(s_knn, s_loc, inds, DE, z);
  k_bnpart  <<<128, 256, 0, stream>>>(z, part, partsq);
  k_bnfin   <<<1, 64, 0, stream>>>(part, partsq, mu, rstd);
  k_out     <<<BNTOT / 4, 256, 0, stream>>>(z, X, mu, rstd, gamma, beta, out);

  (void)in_sizes; (void)n_in; (void)out_size; (void)ws_size;
}

// Round 6
// 258.784 us; speedup vs baseline: 2.2995x; 1.0316x over previous
//
#include <hip/hip_runtime.h>
#include <math.h>

#define BNTOT 8192      // B*N
#define CH    64        // channels
#define KP1   11        // K+1 neighbors
#define NLOC  1568      // B * E  (8 * 196)
#define CAP   1024      // per-row global candidate capacity
#define LCAP  64        // per-row per-block LDS candidate capacity
#define MARGIN 2.5f     // bf16 score-error margin for the filter

typedef __attribute__((ext_vector_type(8))) short short8;   // 8 bf16 (4 VGPRs)
typedef __attribute__((ext_vector_type(4))) float float4v;  // MFMA C/D

// ---------- helpers ----------
__device__ __forceinline__ int pcnt(int p) {
  int lo = p - 4; if (lo < 0) lo = 0; lo += (lo & 1);
  int hi = p; if (hi > 26) hi = 26;
  return (hi >= lo) ? (((hi - lo) >> 1) + 1) : 0;
}
__device__ __forceinline__ float dv2_of(int u) {
  int node = u & 1023;
  int rr = node >> 5, cc = node & 31;
  int dv = KP1 + pcnt(rr) * pcnt(cc);
  return 1.0f / sqrtf((float)dv);
}
__device__ __forceinline__ unsigned short f2bf(float f) {   // RNE fp32->bf16
  unsigned u = __float_as_uint(f);
  unsigned r = (u + 0x7FFFu + ((u >> 16) & 1u)) >> 16;
  return (unsigned short)r;
}
// monotone key: flip fp32 bits so unsigned compare == float compare
__device__ __forceinline__ unsigned long long skey(float s, int idx) {
  unsigned u = __float_as_uint(s);
  u = (u & 0x80000000u) ? ~u : (u | 0x80000000u);
  return ((unsigned long long)u << 32) | (unsigned)idx;
}

// ---------- K0: cast to bf16 + row squared norms (fused) ----------
__global__ void k_cast(const float* __restrict__ X, unsigned short* __restrict__ Xh,
                       float* __restrict__ sq) {
  int g = blockIdx.x * 256 + threadIdx.x;
  int lane = threadIdx.x & 63;
  float v = X[g];
  Xh[g] = f2bf(v);
  float s = v * v;
  #pragma unroll
  for (int off = 32; off >= 1; off >>= 1) s += __shfl_xor(s, off, 64);
  if (lane == 0) sq[g >> 6] = s;
}

// ---------- KA1: partial per-row top-11 over a 128-sample chunk ----------
// grid 1024 = 128 row-groups x 8 chunks; block 256 = 4 waves.
__global__ __launch_bounds__(256)
void k_thrpart(const float* __restrict__ X, const float* __restrict__ sq,
               float* __restrict__ part) {
  const int tid = threadIdx.x, wave = tid >> 6, lane = tid & 63;
  const int rg = blockIdx.x >> 3, chunk = blockIdx.x & 7;
  const int row = rg * 64 + lane;
  float xr[CH];
  {
    const float4* xp = (const float4*)(X + (size_t)row * CH);
    #pragma unroll
    for (int k = 0; k < CH / 4; ++k) {
      float4 v = xp[k];
      xr[4*k+0] = v.x; xr[4*k+1] = v.y; xr[4*k+2] = v.z; xr[4*k+3] = v.w;
    }
  }
  float tv[KP1];
  #pragma unroll
  for (int t = 0; t < KP1; ++t) tv[t] = INFINITY;

  for (int s = 0; s < 32; ++s) {
    int j = __builtin_amdgcn_readfirstlane(((chunk * 4 + wave) * 32 + s) * 8);
    const float* cp = X + (size_t)j * CH;
    float d0 = 0.f, d1 = 0.f, d2 = 0.f, d3 = 0.f;
    #pragma unroll
    for (int k = 0; k < CH / 4; ++k) {
      d0 = fmaf(xr[4*k+0], cp[4*k+0], d0);
      d1 = fmaf(xr[4*k+1], cp[4*k+1], d1);
      d2 = fmaf(xr[4*k+2], cp[4*k+2], d2);
      d3 = fmaf(xr[4*k+3], cp[4*k+3], d3);
    }
    float cv = fmaf(-2.0f, (d0 + d1) + (d2 + d3), sq[j]);
    #pragma unroll
    for (int t = 0; t < KP1; ++t) {
      float lo = fminf(tv[t], cv), hi = fmaxf(tv[t], cv);
      tv[t] = lo; cv = hi;
    }
  }
  __shared__ float ls[4][64][KP1];
  #pragma unroll
  for (int t = 0; t < KP1; ++t) ls[wave][lane][t] = tv[t];
  __syncthreads();
  if (tid < 64) {
    float v[KP1];
    #pragma unroll
    for (int t = 0; t < KP1; ++t) v[t] = ls[0][tid][t];
    #pragma unroll
    for (int w = 1; w < 4; ++w)
      #pragma unroll
      for (int t = 0; t < KP1; ++t) {
        float cv = ls[w][tid][t];
        #pragma unroll
        for (int s2 = 0; s2 < KP1; ++s2) {
          float lo = fminf(v[s2], cv), hi = fmaxf(v[s2], cv);
          v[s2] = lo; cv = hi;
        }
      }
    size_t base = ((size_t)blockIdx.x * 64 + tid) * KP1;
    #pragma unroll
    for (int t = 0; t < KP1; ++t) part[base + t] = v[t];
  }
}

// ---------- KA2: merge 8 chunk-partials -> per-row threshold ----------
__global__ void k_thrmerge(const float* __restrict__ part, float* __restrict__ thr) {
  const int rg = blockIdx.x, lane = threadIdx.x;
  const int row = rg * 64 + lane;
  float v[KP1];
  {
    size_t b0 = ((size_t)(rg * 8) * 64 + lane) * KP1;
    #pragma unroll
    for (int t = 0; t < KP1; ++t) v[t] = part[b0 + t];
  }
  for (int c = 1; c < 8; ++c) {
    size_t b = ((size_t)(rg * 8 + c) * 64 + lane) * KP1;
    #pragma unroll
    for (int t = 0; t < KP1; ++t) {
      float cv = part[b + t];
      #pragma unroll
      for (int s2 = 0; s2 < KP1; ++s2) {
        float lo = fminf(v[s2], cv), hi = fmaxf(v[s2], cv);
        v[s2] = lo; cv = hi;
      }
    }
  }
  thr[row] = v[KP1 - 1] + MARGIN;
}

// ---------- KB: MFMA all-pairs scores + filter -> LDS compaction -> packed cand ----------
// grid 4096 = 128 row-tiles(64 rows) x 32 col-tiles(256 cols); block 256 = 4 waves.
// wave strip = 64 cols, fully unrolled: all 4 B-tiles preloaded in one burst,
// then 32 MFMA + epilogue from registers (single exposed-latency window).
__global__ __launch_bounds__(256)
void k_filter(const unsigned short* __restrict__ Xh, const float* __restrict__ sq,
              const float* __restrict__ thr, int* __restrict__ cnt,
              unsigned short* __restrict__ cand) {
  __shared__ unsigned short lcand[64][LCAP + 2];   // +2 pad: conflict-free epilogue
  __shared__ int lcnt[64];
  __shared__ int lbase[64];

  const int tid = threadIdx.x, wave = tid >> 6, lane = tid & 63;
  const int m = lane & 15, q = lane >> 4;
  const int rowbase = (blockIdx.x >> 5) * 64;
  const int colbase = (blockIdx.x & 31) * 256 + wave * 64;

  if (tid < 64) lcnt[tid] = 0;

  // A fragments: 4 row-subtiles x 2 k-chunks (32 VGPRs)
  short8 a[4][2];
  #pragma unroll
  for (int rt = 0; rt < 4; ++rt)
    #pragma unroll
    for (int kc = 0; kc < 2; ++kc)
      a[rt][kc] = *(const short8*)(Xh + (size_t)(rowbase + rt * 16 + m) * CH + kc * 32 + q * 8);

  // B tiles for all 4 sub-cols + col norms: one load burst
  short8 b0[4], b1[4];
  float sqv[4];
  #pragma unroll
  for (int sub = 0; sub < 4; ++sub) {
    const int coln = colbase + sub * 16 + m;
    const short8* bp = (const short8*)(Xh + (size_t)coln * CH + q * 8);
    b0[sub] = bp[0];
    b1[sub] = bp[4];               // +32 bf16
    sqv[sub] = sq[coln];
  }

  float thrv[16];
  #pragma unroll
  for (int rt = 0; rt < 4; ++rt)
    #pragma unroll
    for (int r = 0; r < 4; ++r)
      thrv[rt * 4 + r] = thr[rowbase + rt * 16 + q * 4 + r];

  __syncthreads();

  const float4v cz = {0.f, 0.f, 0.f, 0.f};
  #pragma unroll
  for (int sub = 0; sub < 4; ++sub) {
    const int coln = colbase + sub * 16 + m;
    #pragma unroll
    for (int rt = 0; rt < 4; ++rt) {
      float4v c = __builtin_amdgcn_mfma_f32_16x16x32_bf16(a[rt][0], b0[sub], cz, 0, 0, 0);
      c = __builtin_amdgcn_mfma_f32_16x16x32_bf16(a[rt][1], b1[sub], c, 0, 0, 0);
      #pragma unroll
      for (int r = 0; r < 4; ++r) {
        float score = fmaf(-2.0f, c[r], sqv[sub]);
        if (score < thrv[rt * 4 + r]) {
          int rl = rt * 16 + q * 4 + r;
          int s = atomicAdd(&lcnt[rl], 1);
          if (s < LCAP) {
            lcand[rl][s] = (unsigned short)coln;
          } else {                                   // rare overflow: direct global
            int gs = atomicAdd(&cnt[rowbase + rl], 1);
            if (gs < CAP) cand[(size_t)(rowbase + rl) * CAP + gs] = (unsigned short)coln;
          }
        }
      }
    }
  }

  __syncthreads();
  if (tid < 64) {
    int nl = lcnt[tid]; if (nl > LCAP) nl = LCAP;
    lbase[tid] = atomicAdd(&cnt[rowbase + tid], nl);
    lcnt[tid] = nl;
  }
  __syncthreads();
  if (tid < 64) {
    int nl = lcnt[tid], base = lbase[tid];
    unsigned short* dst = cand + (size_t)(rowbase + tid) * CAP;
    for (int s = 0; s < nl; ++s) {
      int g = base + s;
      if (g < CAP) dst[g] = lcand[tid][s];
    }
  }
}

// ---------- KC: exact fp32 rescore, one wave per row, no LDS ----------
// grid 2048 x 256 thr; 4 rows/block (one wave each), 64 lanes split candidates.
__global__ __launch_bounds__(256)
void k_rescore(const float* __restrict__ X, const float* __restrict__ sq,
               const int* __restrict__ cnt, const unsigned short* __restrict__ cand,
               int* __restrict__ inds, int* __restrict__ DE) {
  const int tid = threadIdx.x, lane = tid & 63;
  const int row = __builtin_amdgcn_readfirstlane(blockIdx.x * 4 + (tid >> 6));

  float xr[CH];
  {
    const float4* xp = (const float4*)(X + (size_t)row * CH);
    #pragma unroll
    for (int k = 0; k < CH / 4; ++k) {
      float4 v = xp[k];
      xr[4*k+0] = v.x; xr[4*k+1] = v.y; xr[4*k+2] = v.z; xr[4*k+3] = v.w;
    }
  }
  int n = cnt[row]; if (n > CAP) n = CAP;

  float tv[KP1]; int ti[KP1];
  #pragma unroll
  for (int t = 0; t < KP1; ++t) { tv[t] = INFINITY; ti[t] = -1; }

  for (int s = lane; s < n; s += 64) {
    int cj = cand[(size_t)row * CAP + s];
    const float4* cp = (const float4*)(X + (size_t)cj * CH);
    float d0 = 0.f, d1 = 0.f, d2 = 0.f, d3 = 0.f;
    #pragma unroll
    for (int k = 0; k < CH / 4; ++k) {
      float4 v = cp[k];
      d0 = fmaf(xr[4*k+0], v.x, d0);
      d1 = fmaf(xr[4*k+1], v.y, d1);
      d2 = fmaf(xr[4*k+2], v.z, d2);
      d3 = fmaf(xr[4*k+3], v.w, d3);
    }
    float score = fmaf(-2.0f, (d0 + d1) + (d2 + d3), sq[cj]);
    if (score < tv[KP1 - 1]) {
      float cv = score; int ci = cj;
      #pragma unroll
      for (int t = 0; t < KP1; ++t) {
        bool sw = cv < tv[t];
        float nv = sw ? cv   : tv[t]; int ni = sw ? ci   : ti[t];
        float ov = sw ? tv[t] : cv;   int oi = sw ? ti[t] : ci;
        tv[t] = nv; ti[t] = ni; cv = ov; ci = oi;
      }
    }
  }

  // 11 wave-min extractions; idx unique per row -> unique winner each time
  unsigned long long cur = skey(tv[0], ti[0]);
  unsigned long long keep = 0;
  #pragma unroll
  for (int t = 0; t < KP1; ++t) {
    unsigned long long m = cur;
    #pragma unroll
    for (int off = 1; off < 64; off <<= 1) {
      unsigned lo = __shfl_xor((unsigned)m, off, 64);
      unsigned hi = __shfl_xor((unsigned)(m >> 32), off, 64);
      unsigned long long o = ((unsigned long long)hi << 32) | lo;
      m = (o < m) ? o : m;
    }
    if (lane == t) keep = m;
    if (cur == m) {                      // winner pops its front
      #pragma unroll
      for (int q = 0; q < KP1 - 1; ++q) { tv[q] = tv[q+1]; ti[q] = ti[q+1]; }
      tv[KP1-1] = INFINITY; ti[KP1-1] = -1;
      cur = skey(tv[0], ti[0]);
    }
  }
  if (lane < KP1) {
    int idx = (int)(unsigned)(keep & 0xFFFFFFFFu);
    inds[(size_t)row * KP1 + lane] = idx;
    atomicAdd(&DE[idx], 1);
  }
}

// ---------- K3: t = Dv^{-1/2} * (x @ W^T + b) ----------
__global__ void k_lin(const float* __restrict__ X, const float* __restrict__ W,
                      const float* __restrict__ bias, float* __restrict__ t) {
  int lane = threadIdx.x & 63;
  int wave = threadIdx.x >> 6;
  int rowbase = (blockIdx.x * 4 + wave) * 16;
  float wr[CH];
  {
    const float4* wp = (const float4*)(W + (size_t)lane * CH);
    #pragma unroll
    for (int k = 0; k < CH / 4; ++k) {
      float4 v = wp[k];
      wr[4*k+0] = v.x; wr[4*k+1] = v.y; wr[4*k+2] = v.z; wr[4*k+3] = v.w;
    }
  }
  float bc = bias[lane];
  for (int r = 0; r < 16; ++r) {
    int row = __builtin_amdgcn_readfirstlane(rowbase + r);
    const float* xp = X + (size_t)row * CH;
    float d0 = 0.f, d1 = 0.f, d2 = 0.f, d3 = 0.f;
    #pragma unroll
    for (int k = 0; k < CH / 4; ++k) {
      d0 = fmaf(wr[4*k+0], xp[4*k+0], d0);
      d1 = fmaf(wr[4*k+1], xp[4*k+1], d1);
      d2 = fmaf(wr[4*k+2], xp[4*k+2], d2);
      d3 = fmaf(wr[4*k+3], xp[4*k+3], d3);
    }
    float y = (d0 + d1) + (d2 + d3) + bc;
    t[(size_t)row * CH + lane] = y * dv2_of(row);
  }
}

// ---------- K4a: scatter t into KNN edge sums ----------
__global__ void k_scatter(const float* __restrict__ t, const int* __restrict__ inds,
                          float* __restrict__ s_knn) {
  int c = threadIdx.x & 63;
  int u = blockIdx.x * 4 + (threadIdx.x >> 6);
  float val = t[(size_t)u * CH + c];
  int ub = __builtin_amdgcn_readfirstlane(u);
  const int* ip = inds + (size_t)ub * KP1;
  #pragma unroll
  for (int j = 0; j < KP1; ++j) {
    int e = ip[j];
    atomicAdd(&s_knn[(size_t)e * CH + c], val);
  }
}

// ---------- K4b: local patch edge sums, pre-scaled by 1/De (=1/25) ----------
__global__ void k_local(const float* __restrict__ t, float* __restrict__ s_loc) {
  int c = threadIdx.x & 63;
  int e = blockIdx.x * 4 + (threadIdx.x >> 6);
  int b  = e / 196;
  int le = e - b * 196;
  int pi = le / 14;
  int pj = le - pi * 14;
  int base = b * 1024 + (pi * 2) * 32 + pj * 2;
  float acc = 0.f;
  #pragma unroll
  for (int di = 0; di < 5; ++di)
    #pragma unroll
    for (int dj = 0; dj < 5; ++dj)
      acc += t[(size_t)(base + di * 32 + dj) * CH + c];
  s_loc[(size_t)e * CH + c] = acc * (1.0f / 25.0f);
}

// ---------- K5: z[u] = dv2_u * ( sum_knn s_knn[e]/DE[e] + sum_local s_loc[p] ) ----------
__global__ void k_gather(const float* __restrict__ s_knn, const float* __restrict__ s_loc,
                         const int* __restrict__ inds, const int* __restrict__ DE,
                         float* __restrict__ z) {
  int c = threadIdx.x & 63;
  int u = blockIdx.x * 4 + (threadIdx.x >> 6);
  int ub = __builtin_amdgcn_readfirstlane(u);
  const int* ip = inds + (size_t)ub * KP1;
  float acc = 0.f;
  #pragma unroll
  for (int j = 0; j < KP1; ++j) {
    int e = ip[j];
    float invde = 1.0f / (float)DE[e];
    acc += s_knn[(size_t)e * CH + c] * invde;
  }
  int node = ub & 1023, b = ub >> 10;
  int rr = node >> 5, cc = node & 31;
  int i0 = rr - 4; if (i0 < 0) i0 = 0; i0 += (i0 & 1);
  int i1 = rr; if (i1 > 26) i1 = 26;
  int j0 = cc - 4; if (j0 < 0) j0 = 0; j0 += (j0 & 1);
  int j1 = cc; if (j1 > 26) j1 = 26;
  for (int i = i0; i <= i1; i += 2)
    for (int jj = j0; jj <= j1; jj += 2) {
      int e = b * 196 + (i >> 1) * 14 + (jj >> 1);
      acc += s_loc[(size_t)e * CH + c];
    }
  z[(size_t)ub * CH + c] = acc * dv2_of(ub);
}

// ---------- K6a: per-64-row-block partial BN sums ----------
__global__ void k_bnpart(const float* __restrict__ z, float* __restrict__ part,
                         float* __restrict__ partsq) {
  int c = threadIdx.x & 63;
  int rq = threadIdx.x >> 6;
  int blk = blockIdx.x;
  float s = 0.f, s2 = 0.f;
  for (int k = 0; k < 16; ++k) {
    float v = z[(size_t)(blk * 64 + rq * 16 + k) * CH + c];
    s += v; s2 += v * v;
  }
  __shared__ float ls[4][CH], ls2[4][CH];
  ls[rq][c] = s; ls2[rq][c] = s2;
  __syncthreads();
  if (rq == 0) {
    part[(size_t)blk * CH + c]   = ls[0][c] + ls[1][c] + ls[2][c] + ls[3][c];
    partsq[(size_t)blk * CH + c] = ls2[0][c] + ls2[1][c] + ls2[2][c] + ls2[3][c];
  }
}

// ---------- K6b: finalize mu / rstd ----------
__global__ void k_bnfin(const float* __restrict__ part, const float* __restrict__ partsq,
                        float* __restrict__ mu, float* __restrict__ rstd) {
  int c = threadIdx.x;
  float s = 0.f, s2 = 0.f;
  for (int b = 0; b < 128; ++b) { s += part[(size_t)b * CH + c]; s2 += partsq[(size_t)b * CH + c]; }
  float m = s * (1.0f / (float)BNTOT);
  float var = s2 * (1.0f / (float)BNTOT) - m * m;
  mu[c] = m;
  rstd[c] = 1.0f / sqrtf(var + 1e-5f);
}

// ---------- K7: BN apply + relu + residual ----------
__global__ void k_out(const float* __restrict__ z, const float* __restrict__ X,
                      const float* __restrict__ mu, const float* __restrict__ rstd,
                      const float* __restrict__ gamma, const float* __restrict__ beta,
                      float* __restrict__ out) {
  int c = threadIdx.x & 63;
  int u = blockIdx.x * 4 + (threadIdx.x >> 6);
  size_t idx = (size_t)u * CH + c;
  float zn = (z[idx] - mu[c]) * rstd[c] * gamma[c] + beta[c];
  out[idx] = fmaxf(zn, 0.f) + X[idx];
}

// ---------- launch ----------
extern "C" void kernel_launch(void* const* d_in, const int* in_sizes, int n_in,
                              void* d_out, int out_size, void* d_ws, size_t ws_size,
                              hipStream_t stream) {
  const float* X     = (const float*)d_in[0];
  const float* W     = (const float*)d_in[1];
  const float* bias  = (const float*)d_in[2];
  const float* gamma = (const float*)d_in[3];
  const float* beta  = (const float*)d_in[4];
  float* out = (float*)d_out;

  // workspace layout
  float* ws = (float*)d_ws;
  float* sq      = ws;                       // 8192
  float* thr     = sq + 8192;                // 8192
  float* t       = thr + 8192;               // 524288
  float* s_loc   = t + 524288;               // 100352
  float* z       = s_loc + 100352;           // 524288
  float* part    = z + 524288;               // 8192
  float* partsq  = part + 8192;              // 8192
  float* mu      = partsq + 8192;            // 64
  float* rstd    = mu + 64;                  // 64
  float* thrpart = rstd + 64;                // 1024*64*11 = 720896
  int*   inds    = (int*)(thrpart + 720896); // 90112 ints
  unsigned short* Xh   = (unsigned short*)(inds + 90112);   // 524288 shorts
  unsigned short* cand = Xh + 524288;                        // 8192*1024 shorts
  // zeroed region: cnt (8192 int) + DE (8192 int) + s_knn (524288 f), contiguous
  int*   cnt    = (int*)(cand + (size_t)8192 * CAP);
  int*   DE     = cnt + 8192;
  float* s_knn  = (float*)(DE + 8192);

  hipMemsetAsync(cnt, 0, (size_t)(8192 + 8192 + 524288) * 4, stream);

  k_cast    <<<2048, 256, 0, stream>>>(X, Xh, sq);
  k_thrpart <<<1024, 256, 0, stream>>>(X, sq, thrpart);
  k_thrmerge<<<128, 64, 0, stream>>>(thrpart, thr);
  k_filter  <<<4096, 256, 0, stream>>>(Xh, sq, thr, cnt, cand);
  k_rescore <<<2048, 256, 0, stream>>>(X, sq, cnt, cand, inds, DE);
  k_lin     <<<128, 256, 0, stream>>>(X, W, bias, t);
  k_scatter <<<BNTOT / 4, 256, 0, stream>>>(t, inds, s_knn);
  k_local   <<<NLOC / 4, 256, 0, stream>>>(t, s_loc);
  k_gather  <<<BNTOT / 4, 256, 0, stream>>>(s_knn, s_loc, inds, DE, z);
  k_bnpart  <<<128, 256, 0, stream>>>(z, part, partsq);
  k_bnfin   <<<1, 64, 0, stream>>>(part, partsq, mu, rstd);
  k_out     <<<BNTOT / 4, 256, 0, stream>>>(z, X, mu, rstd, gamma, beta, out);

  (void)in_sizes; (void)n_in; (void)out_size; (void)ws_size;
}

// Round 9
// 237.348 us; speedup vs baseline: 2.5071x; 1.0903x over previous
//
#include <hip/hip_runtime.h>
#include <math.h>

#define BNTOT 8192      // B*N
#define CH    64        // channels
#define KP1   11        // K+1 neighbors
#define NLOC  1568      // B * E  (8 * 196)
#define CAP   256       // per-row global candidate capacity (uint2 entries)
#define LCAP  32        // per-row per-block LDS candidate capacity
#define MARGIN 1.0f     // bf16 score-error margin for the filter (>= ~0.4 tail err)
#define DELTA  2.0f     // rescore cutoff slack

typedef __attribute__((ext_vector_type(8))) short short8;   // 8 bf16 (4 VGPRs)
typedef __attribute__((ext_vector_type(4))) float float4v;  // MFMA C/D

// ---------- helpers ----------
__device__ __forceinline__ int pcnt(int p) {
  int lo = p - 4; if (lo < 0) lo = 0; lo += (lo & 1);
  int hi = p; if (hi > 26) hi = 26;
  return (hi >= lo) ? (((hi - lo) >> 1) + 1) : 0;
}
__device__ __forceinline__ float dv2_of(int u) {
  int node = u & 1023;
  int rr = node >> 5, cc = node & 31;
  int dv = KP1 + pcnt(rr) * pcnt(cc);
  return 1.0f / sqrtf((float)dv);
}
__device__ __forceinline__ unsigned short f2bf(float f) {   // RNE fp32->bf16
  unsigned u = __float_as_uint(f);
  unsigned r = (u + 0x7FFFu + ((u >> 16) & 1u)) >> 16;
  return (unsigned short)r;
}
// monotone key: flip fp32 bits so unsigned compare == float compare
__device__ __forceinline__ unsigned long long skey(float s, int idx) {
  unsigned u = __float_as_uint(s);
  u = (u & 0x80000000u) ? ~u : (u | 0x80000000u);
  return ((unsigned long long)u << 32) | (unsigned)idx;
}

// ---------- K0: cast to bf16 + row squared norms (fused) ----------
__global__ void k_cast(const float* __restrict__ X, unsigned short* __restrict__ Xh,
                       float* __restrict__ sq) {
  int g = blockIdx.x * 256 + threadIdx.x;
  int lane = threadIdx.x & 63;
  float v = X[g];
  Xh[g] = f2bf(v);
  float s = v * v;
  #pragma unroll
  for (int off = 32; off >= 1; off >>= 1) s += __shfl_xor(s, off, 64);
  if (lane == 0) sq[g >> 6] = s;
}

// ---------- KA1: partial per-row top-11 over a 128-sample chunk ----------
// grid 1024 = 128 row-groups x 8 chunks; block 256 = 4 waves.
__global__ __launch_bounds__(256)
void k_thrpart(const float* __restrict__ X, const float* __restrict__ sq,
               float* __restrict__ part) {
  const int tid = threadIdx.x, wave = tid >> 6, lane = tid & 63;
  const int rg = blockIdx.x >> 3, chunk = blockIdx.x & 7;
  const int row = rg * 64 + lane;
  float xr[CH];
  {
    const float4* xp = (const float4*)(X + (size_t)row * CH);
    #pragma unroll
    for (int k = 0; k < CH / 4; ++k) {
      float4 v = xp[k];
      xr[4*k+0] = v.x; xr[4*k+1] = v.y; xr[4*k+2] = v.z; xr[4*k+3] = v.w;
    }
  }
  float tv[KP1];
  #pragma unroll
  for (int t = 0; t < KP1; ++t) tv[t] = INFINITY;

  for (int s = 0; s < 32; ++s) {
    int j = __builtin_amdgcn_readfirstlane(((chunk * 4 + wave) * 32 + s) * 8);
    const float* cp = X + (size_t)j * CH;
    float d0 = 0.f, d1 = 0.f, d2 = 0.f, d3 = 0.f;
    #pragma unroll
    for (int k = 0; k < CH / 4; ++k) {
      d0 = fmaf(xr[4*k+0], cp[4*k+0], d0);
      d1 = fmaf(xr[4*k+1], cp[4*k+1], d1);
      d2 = fmaf(xr[4*k+2], cp[4*k+2], d2);
      d3 = fmaf(xr[4*k+3], cp[4*k+3], d3);
    }
    float cv = fmaf(-2.0f, (d0 + d1) + (d2 + d3), sq[j]);
    #pragma unroll
    for (int t = 0; t < KP1; ++t) {
      float lo = fminf(tv[t], cv), hi = fmaxf(tv[t], cv);
      tv[t] = lo; cv = hi;
    }
  }
  __shared__ float ls[4][64][KP1];
  #pragma unroll
  for (int t = 0; t < KP1; ++t) ls[wave][lane][t] = tv[t];
  __syncthreads();
  if (tid < 64) {
    float v[KP1];
    #pragma unroll
    for (int t = 0; t < KP1; ++t) v[t] = ls[0][tid][t];
    #pragma unroll
    for (int w = 1; w < 4; ++w)
      #pragma unroll
      for (int t = 0; t < KP1; ++t) {
        float cv = ls[w][tid][t];
        #pragma unroll
        for (int s2 = 0; s2 < KP1; ++s2) {
          float lo = fminf(v[s2], cv), hi = fmaxf(v[s2], cv);
          v[s2] = lo; cv = hi;
        }
      }
    size_t base = ((size_t)blockIdx.x * 64 + tid) * KP1;
    #pragma unroll
    for (int t = 0; t < KP1; ++t) part[base + t] = v[t];
  }
}

// ---------- KA2: merge 8 chunk-partials -> per-row threshold ----------
__global__ void k_thrmerge(const float* __restrict__ part, float* __restrict__ thr) {
  const int rg = blockIdx.x, lane = threadIdx.x;
  const int row = rg * 64 + lane;
  float v[KP1];
  {
    size_t b0 = ((size_t)(rg * 8) * 64 + lane) * KP1;
    #pragma unroll
    for (int t = 0; t < KP1; ++t) v[t] = part[b0 + t];
  }
  for (int c = 1; c < 8; ++c) {
    size_t b = ((size_t)(rg * 8 + c) * 64 + lane) * KP1;
    #pragma unroll
    for (int t = 0; t < KP1; ++t) {
      float cv = part[b + t];
      #pragma unroll
      for (int s2 = 0; s2 < KP1; ++s2) {
        float lo = fminf(v[s2], cv), hi = fmaxf(v[s2], cv);
        v[s2] = lo; cv = hi;
      }
    }
  }
  thr[row] = v[KP1 - 1] + MARGIN;
}

// ---------- KB: MFMA all-pairs scores + filter -> LDS compaction -> (col,score) ----------
// grid 4096 = 128 row-tiles(64 rows) x 32 col-tiles(256 cols); block 256 = 4 waves.
__global__ __launch_bounds__(256)
void k_filter(const unsigned short* __restrict__ Xh, const float* __restrict__ sq,
              const float* __restrict__ thr, int* __restrict__ cnt,
              uint2* __restrict__ cand) {
  __shared__ uint2 lcand[64][LCAP];
  __shared__ int lcnt[64];
  __shared__ int lbase[64];

  const int tid = threadIdx.x, wave = tid >> 6, lane = tid & 63;
  const int m = lane & 15, q = lane >> 4;
  const int rowbase = (blockIdx.x >> 5) * 64;
  const int colbase = (blockIdx.x & 31) * 256 + wave * 64;

  if (tid < 64) lcnt[tid] = 0;

  // A fragments: 4 row-subtiles x 2 k-chunks (32 VGPRs)
  short8 a[4][2];
  #pragma unroll
  for (int rt = 0; rt < 4; ++rt)
    #pragma unroll
    for (int kc = 0; kc < 2; ++kc)
      a[rt][kc] = *(const short8*)(Xh + (size_t)(rowbase + rt * 16 + m) * CH + kc * 32 + q * 8);

  // B tiles for all 4 sub-cols + col norms: one load burst
  short8 b0[4], b1[4];
  float sqv[4];
  #pragma unroll
  for (int sub = 0; sub < 4; ++sub) {
    const int coln = colbase + sub * 16 + m;
    const short8* bp = (const short8*)(Xh + (size_t)coln * CH + q * 8);
    b0[sub] = bp[0];
    b1[sub] = bp[4];               // +32 bf16
    sqv[sub] = sq[coln];
  }

  float thrv[16];
  #pragma unroll
  for (int rt = 0; rt < 4; ++rt)
    #pragma unroll
    for (int r = 0; r < 4; ++r)
      thrv[rt * 4 + r] = thr[rowbase + rt * 16 + q * 4 + r];

  __syncthreads();

  const float4v cz = {0.f, 0.f, 0.f, 0.f};
  #pragma unroll
  for (int sub = 0; sub < 4; ++sub) {
    const int coln = colbase + sub * 16 + m;
    #pragma unroll
    for (int rt = 0; rt < 4; ++rt) {
      float4v c = __builtin_amdgcn_mfma_f32_16x16x32_bf16(a[rt][0], b0[sub], cz, 0, 0, 0);
      c = __builtin_amdgcn_mfma_f32_16x16x32_bf16(a[rt][1], b1[sub], c, 0, 0, 0);
      #pragma unroll
      for (int r = 0; r < 4; ++r) {
        float score = fmaf(-2.0f, c[r], sqv[sub]);
        if (score < thrv[rt * 4 + r]) {
          int rl = rt * 16 + q * 4 + r;
          uint2 ent; ent.x = (unsigned)coln; ent.y = __float_as_uint(score);
          int s = atomicAdd(&lcnt[rl], 1);
          if (s < LCAP) {
            lcand[rl][s] = ent;
          } else {                                   // rare overflow: direct global
            int gs = atomicAdd(&cnt[rowbase + rl], 1);
            if (gs < CAP) cand[(size_t)(rowbase + rl) * CAP + gs] = ent;
          }
        }
      }
    }
  }

  __syncthreads();
  if (tid < 64) {
    int nl = lcnt[tid]; if (nl > LCAP) nl = LCAP;
    lbase[tid] = atomicAdd(&cnt[rowbase + tid], nl);
    lcnt[tid] = nl;
  }
  __syncthreads();
  if (tid < 64) {
    int nl = lcnt[tid], base = lbase[tid];
    uint2* dst = cand + (size_t)(rowbase + tid) * CAP;
    for (int s = 0; s < nl; ++s) {
      int g = base + s;
      if (g < CAP) dst[g] = lcand[tid][s];
    }
  }
}

// ---------- KC: rescore, one wave per row. Normal path: bf-score prefilter +
// exact survivors. Overflow path (cnt>CAP, truncated list): exact full scan of
// all 8192 columns — correctness never depends on the candidate list there.
__global__ __launch_bounds__(256)
void k_rescore(const float* __restrict__ X, const float* __restrict__ sq,
               const int* __restrict__ cnt, const uint2* __restrict__ cand,
               int* __restrict__ inds, int* __restrict__ DE) {
  const int tid = threadIdx.x, lane = tid & 63;
  const int row = __builtin_amdgcn_readfirstlane(blockIdx.x * 4 + (tid >> 6));

  // own row (wave-uniform address -> scalar loads)
  float xr[CH];
  {
    const float4* xp = (const float4*)(X + (size_t)row * CH);
    #pragma unroll
    for (int k = 0; k < CH / 4; ++k) {
      float4 v = xp[k];
      xr[4*k+0] = v.x; xr[4*k+1] = v.y; xr[4*k+2] = v.z; xr[4*k+3] = v.w;
    }
  }
  const int nraw = cnt[row];

  float tv[KP1]; int ti[KP1];
  #pragma unroll
  for (int t = 0; t < KP1; ++t) { tv[t] = INFINITY; ti[t] = -1; }

  if (nraw <= CAP) {
    const int n = nraw;
    const int slotcnt = (n + 63) >> 6;        // 0..4

    // Phase A: load my candidate slots (coalesced)
    float bsc[4]; int bcol[4];
    #pragma unroll
    for (int a = 0; a < 4; ++a) { bsc[a] = INFINITY; bcol[a] = -1; }
    for (int a = 0; a < slotcnt; ++a) {
      int s = a * 64 + lane;
      if (s < n) {
        uint2 e = cand[(size_t)row * CAP + s];
        bcol[a] = (int)e.x; bsc[a] = __uint_as_float(e.y);
      }
    }
    // per-lane min, then 11 fminf-butterfly extractions (self-pop) -> c11 bound
    float curf = bsc[0];
    #pragma unroll
    for (int a = 1; a < 4; ++a) curf = fminf(curf, bsc[a]);
    float c11 = INFINITY;
    #pragma unroll
    for (int t = 0; t < KP1; ++t) {
      float mw = curf;
      #pragma unroll
      for (int off = 1; off < 64; off <<= 1) mw = fminf(mw, __shfl_xor(mw, off, 64));
      if (t == KP1 - 1) c11 = mw;
      if (curf == mw) curf = INFINITY;      // ties pop together: bound only loosens
    }
    const float cutoff = c11 + DELTA;

    // Phase B: exact gather-dot for survivors; insert into exact sorted-11
    for (int a = 0; a < slotcnt; ++a) {
      if (bsc[a] <= cutoff) {
        int cj = bcol[a];
        const float4* cp = (const float4*)(X + (size_t)cj * CH);
        float d0 = 0.f, d1 = 0.f, d2 = 0.f, d3 = 0.f;
        #pragma unroll
        for (int k = 0; k < CH / 4; ++k) {
          float4 v = cp[k];
          d0 = fmaf(xr[4*k+0], v.x, d0);
          d1 = fmaf(xr[4*k+1], v.y, d1);
          d2 = fmaf(xr[4*k+2], v.z, d2);
          d3 = fmaf(xr[4*k+3], v.w, d3);
        }
        float score = fmaf(-2.0f, (d0 + d1) + (d2 + d3), sq[cj]);
        if (score < tv[KP1 - 1]) {
          float cv = score; int ci = cj;
          #pragma unroll
          for (int t = 0; t < KP1; ++t) {
            bool sw = cv < tv[t];
            float nv = sw ? cv   : tv[t]; int ni = sw ? ci   : ti[t];
            float ov = sw ? tv[t] : cv;   int oi = sw ? ti[t] : ci;
            tv[t] = nv; ti[t] = ni; cv = ov; ci = oi;
          }
        }
      }
    }
  } else {
    // Fallback: candidate list truncated -> exact full scan (round-5-proven loop)
    for (int s = lane; s < BNTOT; s += 64) {
      const float4* cp = (const float4*)(X + (size_t)s * CH);
      float d0 = 0.f, d1 = 0.f, d2 = 0.f, d3 = 0.f;
      #pragma unroll
      for (int k = 0; k < CH / 4; ++k) {
        float4 v = cp[k];
        d0 = fmaf(xr[4*k+0], v.x, d0);
        d1 = fmaf(xr[4*k+1], v.y, d1);
        d2 = fmaf(xr[4*k+2], v.z, d2);
        d3 = fmaf(xr[4*k+3], v.w, d3);
      }
      float score = fmaf(-2.0f, (d0 + d1) + (d2 + d3), sq[s]);
      if (score < tv[KP1 - 1]) {
        float cv = score; int ci = s;
        #pragma unroll
        for (int t = 0; t < KP1; ++t) {
          bool sw = cv < tv[t];
          float nv = sw ? cv   : tv[t]; int ni = sw ? ci   : ti[t];
          float ov = sw ? tv[t] : cv;   int oi = sw ? ti[t] : ci;
          tv[t] = nv; ti[t] = ni; cv = ov; ci = oi;
        }
      }
    }
  }

  // Phase C: 11 wave-min extractions on u64 keys (round-6 proven)
  unsigned long long cur = skey(tv[0], ti[0]);
  unsigned long long keep = 0;
  #pragma unroll
  for (int t = 0; t < KP1; ++t) {
    unsigned long long mw = cur;
    #pragma unroll
    for (int off = 1; off < 64; off <<= 1) {
      unsigned lo = __shfl_xor((unsigned)mw, off, 64);
      unsigned hi = __shfl_xor((unsigned)(mw >> 32), off, 64);
      unsigned long long o = ((unsigned long long)hi << 32) | lo;
      mw = (o < mw) ? o : mw;
    }
    if (lane == t) keep = mw;
    if (cur == mw) {                      // winner pops its front
      #pragma unroll
      for (int q = 0; q < KP1 - 1; ++q) { tv[q] = tv[q+1]; ti[q] = ti[q+1]; }
      tv[KP1-1] = INFINITY; ti[KP1-1] = -1;
      cur = skey(tv[0], ti[0]);
    }
  }
  if (lane < KP1) {
    int idx = (int)(unsigned)(keep & 0xFFFFFFFFull);
    inds[(size_t)row * KP1 + lane] = idx;
    atomicAdd(&DE[idx], 1);
  }
}

// ---------- K3: t = Dv^{-1/2} * (x @ W^T + b) ----------
// grid 512: 4 waves/block x 4 rows/wave.
__global__ void k_lin(const float* __restrict__ X, const float* __restrict__ W,
                      const float* __restrict__ bias, float* __restrict__ t) {
  int lane = threadIdx.x & 63;
  int wave = threadIdx.x >> 6;
  int rowbase = (blockIdx.x * 4 + wave) * 4;
  float wr[CH];
  {
    const float4* wp = (const float4*)(W + (size_t)lane * CH);
    #pragma unroll
    for (int k = 0; k < CH / 4; ++k) {
      float4 v = wp[k];
      wr[4*k+0] = v.x; wr[4*k+1] = v.y; wr[4*k+2] = v.z; wr[4*k+3] = v.w;
    }
  }
  float bc = bias[lane];
  #pragma unroll
  for (int r = 0; r < 4; ++r) {
    int row = __builtin_amdgcn_readfirstlane(rowbase + r);
    const float* xp = X + (size_t)row * CH;
    float d0 = 0.f, d1 = 0.f, d2 = 0.f, d3 = 0.f;
    #pragma unroll
    for (int k = 0; k < CH / 4; ++k) {
      d0 = fmaf(wr[4*k+0], xp[4*k+0], d0);
      d1 = fmaf(wr[4*k+1], xp[4*k+1], d1);
      d2 = fmaf(wr[4*k+2], xp[4*k+2], d2);
      d3 = fmaf(wr[4*k+3], xp[4*k+3], d3);
    }
    float y = (d0 + d1) + (d2 + d3) + bc;
    t[(size_t)row * CH + lane] = y * dv2_of(row);
  }
}

// ---------- K4a: scatter t into KNN edge sums ----------
__global__ void k_scatter(const float* __restrict__ t, const int* __restrict__ inds,
                          float* __restrict__ s_knn) {
  int c = threadIdx.x & 63;
  int u = blockIdx.x * 4 + (threadIdx.x >> 6);
  float val = t[(size_t)u * CH + c];
  int ub = __builtin_amdgcn_readfirstlane(u);
  const int* ip = inds + (size_t)ub * KP1;
  #pragma unroll
  for (int j = 0; j < KP1; ++j) {
    int e = ip[j];
    atomicAdd(&s_knn[(size_t)e * CH + c], val);
  }
}

// ---------- K4b: local patch edge sums, pre-scaled by 1/De (=1/25) ----------
__global__ void k_local(const float* __restrict__ t, float* __restrict__ s_loc) {
  int c = threadIdx.x & 63;
  int e = blockIdx.x * 4 + (threadIdx.x >> 6);
  int b  = e / 196;
  int le = e - b * 196;
  int pi = le / 14;
  int pj = le - pi * 14;
  int base = b * 1024 + (pi * 2) * 32 + pj * 2;
  float acc = 0.f;
  #pragma unroll
  for (int di = 0; di < 5; ++di)
    #pragma unroll
    for (int dj = 0; dj < 5; ++dj)
      acc += t[(size_t)(base + di * 32 + dj) * CH + c];
  s_loc[(size_t)e * CH + c] = acc * (1.0f / 25.0f);
}

// ---------- K5: z[u] = dv2_u * ( sum_knn s_knn[e]/DE[e] + sum_local s_loc[p] ) ----------
__global__ void k_gather(const float* __restrict__ s_knn, const float* __restrict__ s_loc,
                         const int* __restrict__ inds, const int* __restrict__ DE,
                         float* __restrict__ z) {
  int c = threadIdx.x & 63;
  int u = blockIdx.x * 4 + (threadIdx.x >> 6);
  int ub = __builtin_amdgcn_readfirstlane(u);
  const int* ip = inds + (size_t)ub * KP1;
  float acc = 0.f;
  #pragma unroll
  for (int j = 0; j < KP1; ++j) {
    int e = ip[j];
    float invde = 1.0f / (float)DE[e];
    acc += s_knn[(size_t)e * CH + c] * invde;
  }
  int node = ub & 1023, b = ub >> 10;
  int rr = node >> 5, cc = node & 31;
  int i0 = rr - 4; if (i0 < 0) i0 = 0; i0 += (i0 & 1);
  int i1 = rr; if (i1 > 26) i1 = 26;
  int j0 = cc - 4; if (j0 < 0) j0 = 0; j0 += (j0 & 1);
  int j1 = cc; if (j1 > 26) j1 = 26;
  for (int i = i0; i <= i1; i += 2)
    for (int jj = j0; jj <= j1; jj += 2) {
      int e = b * 196 + (i >> 1) * 14 + (jj >> 1);
      acc += s_loc[(size_t)e * CH + c];
    }
  z[(size_t)ub * CH + c] = acc * dv2_of(ub);
}

// ---------- K6a: per-64-row-block partial BN sums ----------
__global__ void k_bnpart(const float* __restrict__ z, float* __restrict__ part,
                         float* __restrict__ partsq) {
  int c = threadIdx.x & 63;
  int rq = threadIdx.x >> 6;
  int blk = blockIdx.x;
  float s = 0.f, s2 = 0.f;
  for (int k = 0; k < 16; ++k) {
    float v = z[(size_t)(blk * 64 + rq * 16 + k) * CH + c];
    s += v; s2 += v * v;
  }
  __shared__ float ls[4][CH], ls2[4][CH];
  ls[rq][c] = s; ls2[rq][c] = s2;
  __syncthreads();
  if (rq == 0) {
    part[(size_t)blk * CH + c]   = ls[0][c] + ls[1][c] + ls[2][c] + ls[3][c];
    partsq[(size_t)blk * CH + c] = ls2[0][c] + ls2[1][c] + ls2[2][c] + ls2[3][c];
  }
}

// ---------- K6b: finalize mu / rstd ----------
__global__ void k_bnfin(const float* __restrict__ part, const float* __restrict__ partsq,
                        float* __restrict__ mu, float* __restrict__ rstd) {
  int c = threadIdx.x;
  float s = 0.f, s2 = 0.f;
  for (int b = 0; b < 128; ++b) { s += part[(size_t)b * CH + c]; s2 += partsq[(size_t)b * CH + c]; }
  float m = s * (1.0f / (float)BNTOT);
  float var = s2 * (1.0f / (float)BNTOT) - m * m;
  mu[c] = m;
  rstd[c] = 1.0f / sqrtf(var + 1e-5f);
}

// ---------- K7: BN apply + relu + residual ----------
__global__ void k_out(const float* __restrict__ z, const float* __restrict__ X,
                      const float* __restrict__ mu, const float* __restrict__ rstd,
                      const float* __restrict__ gamma, const float* __restrict__ beta,
                      float* __restrict__ out) {
  int c = threadIdx.x & 63;
  int u = blockIdx.x * 4 + (threadIdx.x >> 6);
  size_t idx = (size_t)u * CH + c;
  float zn = (z[idx] - mu[c]) * rstd[c] * gamma[c] + beta[c];
  out[idx] = fmaxf(zn, 0.f) + X[idx];
}

// ---------- launch ----------
extern "C" void kernel_launch(void* const* d_in, const int* in_sizes, int n_in,
                              void* d_out, int out_size, void* d_ws, size_t ws_size,
                              hipStream_t stream) {
  const float* X     = (const float*)d_in[0];
  const float* W     = (const float*)d_in[1];
  const float* bias  = (const float*)d_in[2];
  const float* gamma = (const float*)d_in[3];
  const float* beta  = (const float*)d_in[4];
  float* out = (float*)d_out;

  // workspace layout
  float* ws = (float*)d_ws;
  float* sq      = ws;                       // 8192
  float* thr     = sq + 8192;                // 8192
  float* t       = thr + 8192;               // 524288
  float* s_loc   = t + 524288;               // 100352
  float* z       = s_loc + 100352;           // 524288
  float* part    = z + 524288;               // 8192
  float* partsq  = part + 8192;              // 8192
  float* mu      = partsq + 8192;            // 64
  float* rstd    = mu + 64;                  // 64
  float* thrpart = rstd + 64;                // 1024*64*11 = 720896
  int*   inds    = (int*)(thrpart + 720896); // 90112 ints
  unsigned short* Xh = (unsigned short*)(inds + 90112);   // 524288 shorts
  uint2* cand    = (uint2*)(Xh + 524288);                 // 8192*256 uint2 = 16 MB
  // zeroed region: cnt (8192 int) + DE (8192 int) + s_knn (524288 f), contiguous
  int*   cnt    = (int*)(cand + (size_t)8192 * CAP);
  int*   DE     = cnt + 8192;
  float* s_knn  = (float*)(DE + 8192);

  hipMemsetAsync(cnt, 0, (size_t)(8192 + 8192 + 524288) * 4, stream);

  k_cast    <<<2048, 256, 0, stream>>>(X, Xh, sq);
  k_thrpart <<<1024, 256, 0, stream>>>(X, sq, thrpart);
  k_thrmerge<<<128, 64, 0, stream>>>(thrpart, thr);
  k_filter  <<<4096, 256, 0, stream>>>(Xh, sq, thr, cnt, cand);
  k_rescore <<<2048, 256, 0, stream>>>(X, sq, cnt, cand, inds, DE);
  k_lin     <<<512, 256, 0, stream>>>(X, W, bias, t);
  k_scatter <<<BNTOT / 4, 256, 0, stream>>>(t, inds, s_knn);
  k_local   <<<NLOC / 4, 256, 0, stream>>>(t, s_loc);
  k_gather  <<<BNTOT / 4, 256, 0, stream>>>(s_knn, s_loc, inds, DE, z);
  k_bnpart  <<<128, 256, 0, stream>>>(z, part, partsq);
  k_bnfin   <<<1, 64, 0, stream>>>(part, partsq, mu, rstd);
  k_out     <<<BNTOT / 4, 256, 0, stream>>>(z, X, mu, rstd, gamma, beta, out);

  (void)in_sizes; (void)n_in; (void)out_size; (void)ws_size;
}

// Round 10
// 237.086 us; speedup vs baseline: 2.5099x; 1.0011x over previous
//
#include <hip/hip_runtime.h>
#include <math.h>

#define BNTOT 8192      // B*N
#define CH    64        // channels
#define KP1   11        // K+1 neighbors
#define NLOC  1568      // B * E  (8 * 196)
#define CAP   256       // per-row global candidate capacity (uint2 entries)
#define LCAP  32        // per-row per-block LDS candidate capacity
#define MARGIN 1.0f     // bf16 score-error margin for the filter (>= ~0.4 tail err)
#define DELTA  2.0f     // rescore cutoff slack

typedef __attribute__((ext_vector_type(8))) short short8;   // 8 bf16 (4 VGPRs)
typedef __attribute__((ext_vector_type(4))) float float4v;  // MFMA C/D

// ---------- helpers ----------
__device__ __forceinline__ int pcnt(int p) {
  int lo = p - 4; if (lo < 0) lo = 0; lo += (lo & 1);
  int hi = p; if (hi > 26) hi = 26;
  return (hi >= lo) ? (((hi - lo) >> 1) + 1) : 0;
}
__device__ __forceinline__ float dv2_of(int u) {
  int node = u & 1023;
  int rr = node >> 5, cc = node & 31;
  int dv = KP1 + pcnt(rr) * pcnt(cc);
  return 1.0f / sqrtf((float)dv);
}
__device__ __forceinline__ unsigned short f2bf(float f) {   // RNE fp32->bf16
  unsigned u = __float_as_uint(f);
  unsigned r = (u + 0x7FFFu + ((u >> 16) & 1u)) >> 16;
  return (unsigned short)r;
}
// monotone key: flip fp32 bits so unsigned compare == float compare
__device__ __forceinline__ unsigned long long skey(float s, int idx) {
  unsigned u = __float_as_uint(s);
  u = (u & 0x80000000u) ? ~u : (u | 0x80000000u);
  return ((unsigned long long)u << 32) | (unsigned)idx;
}

// ---------- K0: cast to bf16 + row squared norms (fused) ----------
__global__ void k_cast(const float* __restrict__ X, unsigned short* __restrict__ Xh,
                       float* __restrict__ sq) {
  int g = blockIdx.x * 256 + threadIdx.x;
  int lane = threadIdx.x & 63;
  float v = X[g];
  Xh[g] = f2bf(v);
  float s = v * v;
  #pragma unroll
  for (int off = 32; off >= 1; off >>= 1) s += __shfl_xor(s, off, 64);
  if (lane == 0) sq[g >> 6] = s;
}

// ---------- KA1: partial per-row top-11 over a 128-sample chunk ----------
// grid 1024 = 128 row-groups x 8 chunks; block 256 = 4 waves.
__global__ __launch_bounds__(256)
void k_thrpart(const float* __restrict__ X, const float* __restrict__ sq,
               float* __restrict__ part) {
  const int tid = threadIdx.x, wave = tid >> 6, lane = tid & 63;
  const int rg = blockIdx.x >> 3, chunk = blockIdx.x & 7;
  const int row = rg * 64 + lane;
  float xr[CH];
  {
    const float4* xp = (const float4*)(X + (size_t)row * CH);
    #pragma unroll
    for (int k = 0; k < CH / 4; ++k) {
      float4 v = xp[k];
      xr[4*k+0] = v.x; xr[4*k+1] = v.y; xr[4*k+2] = v.z; xr[4*k+3] = v.w;
    }
  }
  float tv[KP1];
  #pragma unroll
  for (int t = 0; t < KP1; ++t) tv[t] = INFINITY;

  for (int s = 0; s < 32; ++s) {
    int j = __builtin_amdgcn_readfirstlane(((chunk * 4 + wave) * 32 + s) * 8);
    const float* cp = X + (size_t)j * CH;
    float d0 = 0.f, d1 = 0.f, d2 = 0.f, d3 = 0.f;
    #pragma unroll
    for (int k = 0; k < CH / 4; ++k) {
      d0 = fmaf(xr[4*k+0], cp[4*k+0], d0);
      d1 = fmaf(xr[4*k+1], cp[4*k+1], d1);
      d2 = fmaf(xr[4*k+2], cp[4*k+2], d2);
      d3 = fmaf(xr[4*k+3], cp[4*k+3], d3);
    }
    float cv = fmaf(-2.0f, (d0 + d1) + (d2 + d3), sq[j]);
    #pragma unroll
    for (int t = 0; t < KP1; ++t) {
      float lo = fminf(tv[t], cv), hi = fmaxf(tv[t], cv);
      tv[t] = lo; cv = hi;
    }
  }
  __shared__ float ls[4][64][KP1];
  #pragma unroll
  for (int t = 0; t < KP1; ++t) ls[wave][lane][t] = tv[t];
  __syncthreads();
  if (tid < 64) {
    float v[KP1];
    #pragma unroll
    for (int t = 0; t < KP1; ++t) v[t] = ls[0][tid][t];
    #pragma unroll
    for (int w = 1; w < 4; ++w)
      #pragma unroll
      for (int t = 0; t < KP1; ++t) {
        float cv = ls[w][tid][t];
        #pragma unroll
        for (int s2 = 0; s2 < KP1; ++s2) {
          float lo = fminf(v[s2], cv), hi = fmaxf(v[s2], cv);
          v[s2] = lo; cv = hi;
        }
      }
    size_t base = ((size_t)blockIdx.x * 64 + tid) * KP1;
    #pragma unroll
    for (int t = 0; t < KP1; ++t) part[base + t] = v[t];
  }
}

// ---------- KA2: merge 8 chunk-partials -> per-row threshold ----------
__global__ void k_thrmerge(const float* __restrict__ part, float* __restrict__ thr) {
  const int rg = blockIdx.x, lane = threadIdx.x;
  const int row = rg * 64 + lane;
  float v[KP1];
  {
    size_t b0 = ((size_t)(rg * 8) * 64 + lane) * KP1;
    #pragma unroll
    for (int t = 0; t < KP1; ++t) v[t] = part[b0 + t];
  }
  for (int c = 1; c < 8; ++c) {
    size_t b = ((size_t)(rg * 8 + c) * 64 + lane) * KP1;
    #pragma unroll
    for (int t = 0; t < KP1; ++t) {
      float cv = part[b + t];
      #pragma unroll
      for (int s2 = 0; s2 < KP1; ++s2) {
        float lo = fminf(v[s2], cv), hi = fmaxf(v[s2], cv);
        v[s2] = lo; cv = hi;
      }
    }
  }
  thr[row] = v[KP1 - 1] + MARGIN;
}

// ---------- KB: MFMA all-pairs scores + filter -> LDS compaction -> (col,score) ----------
// grid 4096 = 128 row-tiles(64 rows) x 32 col-tiles(256 cols); block 256 = 4 waves.
// Epilogue: per (sub,rt) 4-bit pass mask + ffs loop -> atomics only for actual
// survivors (no per-score branch clusters). lcand padded to kill bank conflicts.
__global__ __launch_bounds__(256)
void k_filter(const unsigned short* __restrict__ Xh, const float* __restrict__ sq,
              const float* __restrict__ thr, int* __restrict__ cnt,
              uint2* __restrict__ cand) {
  __shared__ uint2 lcand[64][LCAP + 1];   // +1 pad: 264B stride -> 2-way (free)
  __shared__ int lcnt[64];
  __shared__ int lbase[64];

  const int tid = threadIdx.x, wave = tid >> 6, lane = tid & 63;
  const int m = lane & 15, q = lane >> 4;
  const int rowbase = (blockIdx.x >> 5) * 64;
  const int colbase = (blockIdx.x & 31) * 256 + wave * 64;

  if (tid < 64) lcnt[tid] = 0;

  // A fragments: 4 row-subtiles x 2 k-chunks (32 VGPRs)
  short8 a[4][2];
  #pragma unroll
  for (int rt = 0; rt < 4; ++rt)
    #pragma unroll
    for (int kc = 0; kc < 2; ++kc)
      a[rt][kc] = *(const short8*)(Xh + (size_t)(rowbase + rt * 16 + m) * CH + kc * 32 + q * 8);

  // B tiles for all 4 sub-cols + col norms: one load burst
  short8 b0[4], b1[4];
  float sqv[4];
  #pragma unroll
  for (int sub = 0; sub < 4; ++sub) {
    const int coln = colbase + sub * 16 + m;
    const short8* bp = (const short8*)(Xh + (size_t)coln * CH + q * 8);
    b0[sub] = bp[0];
    b1[sub] = bp[4];               // +32 bf16
    sqv[sub] = sq[coln];
  }

  float thrv[16];
  #pragma unroll
  for (int rt = 0; rt < 4; ++rt)
    #pragma unroll
    for (int r = 0; r < 4; ++r)
      thrv[rt * 4 + r] = thr[rowbase + rt * 16 + q * 4 + r];

  __syncthreads();

  const float4v cz = {0.f, 0.f, 0.f, 0.f};
  #pragma unroll
  for (int sub = 0; sub < 4; ++sub) {
    const int coln = colbase + sub * 16 + m;
    #pragma unroll
    for (int rt = 0; rt < 4; ++rt) {
      float4v c = __builtin_amdgcn_mfma_f32_16x16x32_bf16(a[rt][0], b0[sub], cz, 0, 0, 0);
      c = __builtin_amdgcn_mfma_f32_16x16x32_bf16(a[rt][1], b1[sub], c, 0, 0, 0);
      // branchless 4-bit pass mask + score regs
      float s0 = fmaf(-2.0f, c[0], sqv[sub]);
      float s1 = fmaf(-2.0f, c[1], sqv[sub]);
      float s2 = fmaf(-2.0f, c[2], sqv[sub]);
      float s3 = fmaf(-2.0f, c[3], sqv[sub]);
      unsigned m4 = 0;
      m4 |= (s0 < thrv[rt * 4 + 0]) ? 1u : 0u;
      m4 |= (s1 < thrv[rt * 4 + 1]) ? 2u : 0u;
      m4 |= (s2 < thrv[rt * 4 + 2]) ? 4u : 0u;
      m4 |= (s3 < thrv[rt * 4 + 3]) ? 8u : 0u;
      while (__any(m4 != 0)) {
        if (m4) {
          int i = __ffs(m4) - 1;
          m4 &= m4 - 1;
          float score = (i == 0) ? s0 : (i == 1) ? s1 : (i == 2) ? s2 : s3;
          int rl = rt * 16 + q * 4 + i;
          uint2 ent; ent.x = (unsigned)coln; ent.y = __float_as_uint(score);
          int s = atomicAdd(&lcnt[rl], 1);
          if (s < LCAP) {
            lcand[rl][s] = ent;
          } else {                                   // rare overflow: direct global
            int gs = atomicAdd(&cnt[rowbase + rl], 1);
            if (gs < CAP) cand[(size_t)(rowbase + rl) * CAP + gs] = ent;
          }
        }
      }
    }
  }

  __syncthreads();
  if (tid < 64) {
    int nl = lcnt[tid]; if (nl > LCAP) nl = LCAP;
    lbase[tid] = atomicAdd(&cnt[rowbase + tid], nl);
    lcnt[tid] = nl;
  }
  __syncthreads();
  if (tid < 64) {
    int nl = lcnt[tid], base = lbase[tid];
    uint2* dst = cand + (size_t)(rowbase + tid) * CAP;
    for (int s = 0; s < nl; ++s) {
      int g = base + s;
      if (g < CAP) dst[g] = lcand[tid][s];
    }
  }
}

// ---------- KC: rescore, one wave per row. Normal path: bf-score prefilter +
// exact survivors. Overflow path (cnt>CAP, truncated list): exact full scan of
// all 8192 columns — correctness never depends on the candidate list there.
__global__ __launch_bounds__(256)
void k_rescore(const float* __restrict__ X, const float* __restrict__ sq,
               const int* __restrict__ cnt, const uint2* __restrict__ cand,
               int* __restrict__ inds, int* __restrict__ DE) {
  const int tid = threadIdx.x, lane = tid & 63;
  const int row = __builtin_amdgcn_readfirstlane(blockIdx.x * 4 + (tid >> 6));

  // own row (wave-uniform address -> scalar loads)
  float xr[CH];
  {
    const float4* xp = (const float4*)(X + (size_t)row * CH);
    #pragma unroll
    for (int k = 0; k < CH / 4; ++k) {
      float4 v = xp[k];
      xr[4*k+0] = v.x; xr[4*k+1] = v.y; xr[4*k+2] = v.z; xr[4*k+3] = v.w;
    }
  }
  const int nraw = cnt[row];

  float tv[KP1]; int ti[KP1];
  #pragma unroll
  for (int t = 0; t < KP1; ++t) { tv[t] = INFINITY; ti[t] = -1; }

  if (nraw <= CAP) {
    const int n = nraw;
    const int slotcnt = (n + 63) >> 6;        // 0..4

    // Phase A: load my candidate slots (coalesced)
    float bsc[4]; int bcol[4];
    #pragma unroll
    for (int a = 0; a < 4; ++a) { bsc[a] = INFINITY; bcol[a] = -1; }
    for (int a = 0; a < slotcnt; ++a) {
      int s = a * 64 + lane;
      if (s < n) {
        uint2 e = cand[(size_t)row * CAP + s];
        bcol[a] = (int)e.x; bsc[a] = __uint_as_float(e.y);
      }
    }
    // per-lane min, then 11 fminf-butterfly extractions (self-pop) -> c11 bound
    float curf = bsc[0];
    #pragma unroll
    for (int a = 1; a < 4; ++a) curf = fminf(curf, bsc[a]);
    float c11 = INFINITY;
    #pragma unroll
    for (int t = 0; t < KP1; ++t) {
      float mw = curf;
      #pragma unroll
      for (int off = 1; off < 64; off <<= 1) mw = fminf(mw, __shfl_xor(mw, off, 64));
      if (t == KP1 - 1) c11 = mw;
      if (curf == mw) curf = INFINITY;      // ties pop together: bound only loosens
    }
    const float cutoff = c11 + DELTA;

    // Phase B: exact gather-dot for survivors; insert into exact sorted-11
    for (int a = 0; a < slotcnt; ++a) {
      if (bsc[a] <= cutoff) {
        int cj = bcol[a];
        const float4* cp = (const float4*)(X + (size_t)cj * CH);
        float d0 = 0.f, d1 = 0.f, d2 = 0.f, d3 = 0.f;
        #pragma unroll
        for (int k = 0; k < CH / 4; ++k) {
          float4 v = cp[k];
          d0 = fmaf(xr[4*k+0], v.x, d0);
          d1 = fmaf(xr[4*k+1], v.y, d1);
          d2 = fmaf(xr[4*k+2], v.z, d2);
          d3 = fmaf(xr[4*k+3], v.w, d3);
        }
        float score = fmaf(-2.0f, (d0 + d1) + (d2 + d3), sq[cj]);
        if (score < tv[KP1 - 1]) {
          float cv = score; int ci = cj;
          #pragma unroll
          for (int t = 0; t < KP1; ++t) {
            bool sw = cv < tv[t];
            float nv = sw ? cv   : tv[t]; int ni = sw ? ci   : ti[t];
            float ov = sw ? tv[t] : cv;   int oi = sw ? ti[t] : ci;
            tv[t] = nv; ti[t] = ni; cv = ov; ci = oi;
          }
        }
      }
    }
  } else {
    // Fallback: candidate list truncated -> exact full scan (round-5-proven loop)
    for (int s = lane; s < BNTOT; s += 64) {
      const float4* cp = (const float4*)(X + (size_t)s * CH);
      float d0 = 0.f, d1 = 0.f, d2 = 0.f, d3 = 0.f;
      #pragma unroll
      for (int k = 0; k < CH / 4; ++k) {
        float4 v = cp[k];
        d0 = fmaf(xr[4*k+0], v.x, d0);
        d1 = fmaf(xr[4*k+1], v.y, d1);
        d2 = fmaf(xr[4*k+2], v.z, d2);
        d3 = fmaf(xr[4*k+3], v.w, d3);
      }
      float score = fmaf(-2.0f, (d0 + d1) + (d2 + d3), sq[s]);
      if (score < tv[KP1 - 1]) {
        float cv = score; int ci = s;
        #pragma unroll
        for (int t = 0; t < KP1; ++t) {
          bool sw = cv < tv[t];
          float nv = sw ? cv   : tv[t]; int ni = sw ? ci   : ti[t];
          float ov = sw ? tv[t] : cv;   int oi = sw ? ti[t] : ci;
          tv[t] = nv; ti[t] = ni; cv = ov; ci = oi;
        }
      }
    }
  }

  // Phase C: 11 wave-min extractions on u64 keys (round-6 proven)
  unsigned long long cur = skey(tv[0], ti[0]);
  unsigned long long keep = 0;
  #pragma unroll
  for (int t = 0; t < KP1; ++t) {
    unsigned long long mw = cur;
    #pragma unroll
    for (int off = 1; off < 64; off <<= 1) {
      unsigned lo = __shfl_xor((unsigned)mw, off, 64);
      unsigned hi = __shfl_xor((unsigned)(mw >> 32), off, 64);
      unsigned long long o = ((unsigned long long)hi << 32) | lo;
      mw = (o < mw) ? o : mw;
    }
    if (lane == t) keep = mw;
    if (cur == mw) {                      // winner pops its front
      #pragma unroll
      for (int q = 0; q < KP1 - 1; ++q) { tv[q] = tv[q+1]; ti[q] = ti[q+1]; }
      tv[KP1-1] = INFINITY; ti[KP1-1] = -1;
      cur = skey(tv[0], ti[0]);
    }
  }
  if (lane < KP1) {
    int idx = (int)(unsigned)(keep & 0xFFFFFFFFull);
    inds[(size_t)row * KP1 + lane] = idx;
    atomicAdd(&DE[idx], 1);
  }
}

// ---------- K3: t = Dv^{-1/2} * (x @ W^T + b) ----------
// grid 512: 4 waves/block x 4 rows/wave.
__global__ void k_lin(const float* __restrict__ X, const float* __restrict__ W,
                      const float* __restrict__ bias, float* __restrict__ t) {
  int lane = threadIdx.x & 63;
  int wave = threadIdx.x >> 6;
  int rowbase = (blockIdx.x * 4 + wave) * 4;
  float wr[CH];
  {
    const float4* wp = (const float4*)(W + (size_t)lane * CH);
    #pragma unroll
    for (int k = 0; k < CH / 4; ++k) {
      float4 v = wp[k];
      wr[4*k+0] = v.x; wr[4*k+1] = v.y; wr[4*k+2] = v.z; wr[4*k+3] = v.w;
    }
  }
  float bc = bias[lane];
  #pragma unroll
  for (int r = 0; r < 4; ++r) {
    int row = __builtin_amdgcn_readfirstlane(rowbase + r);
    const float* xp = X + (size_t)row * CH;
    float d0 = 0.f, d1 = 0.f, d2 = 0.f, d3 = 0.f;
    #pragma unroll
    for (int k = 0; k < CH / 4; ++k) {
      d0 = fmaf(wr[4*k+0], xp[4*k+0], d0);
      d1 = fmaf(wr[4*k+1], xp[4*k+1], d1);
      d2 = fmaf(wr[4*k+2], xp[4*k+2], d2);
      d3 = fmaf(wr[4*k+3], xp[4*k+3], d3);
    }
    float y = (d0 + d1) + (d2 + d3) + bc;
    t[(size_t)row * CH + lane] = y * dv2_of(row);
  }
}

// ---------- K4a: scatter t into KNN edge sums ----------
__global__ void k_scatter(const float* __restrict__ t, const int* __restrict__ inds,
                          float* __restrict__ s_knn) {
  int c = threadIdx.x & 63;
  int u = blockIdx.x * 4 + (threadIdx.x >> 6);
  float val = t[(size_t)u * CH + c];
  int ub = __builtin_amdgcn_readfirstlane(u);
  const int* ip = inds + (size_t)ub * KP1;
  #pragma unroll
  for (int j = 0; j < KP1; ++j) {
    int e = ip[j];
    atomicAdd(&s_knn[(size_t)e * CH + c], val);
  }
}

// ---------- K4b: local patch edge sums, pre-scaled by 1/De (=1/25) ----------
__global__ void k_local(const float* __restrict__ t, float* __restrict__ s_loc) {
  int c = threadIdx.x & 63;
  int e = blockIdx.x * 4 + (threadIdx.x >> 6);
  int b  = e / 196;
  int le = e - b * 196;
  int pi = le / 14;
  int pj = le - pi * 14;
  int base = b * 1024 + (pi * 2) * 32 + pj * 2;
  float acc = 0.f;
  #pragma unroll
  for (int di = 0; di < 5; ++di)
    #pragma unroll
    for (int dj = 0; dj < 5; ++dj)
      acc += t[(size_t)(base + di * 32 + dj) * CH + c];
  s_loc[(size_t)e * CH + c] = acc * (1.0f / 25.0f);
}

// ---------- K5: z[u] = dv2_u * ( sum_knn s_knn[e]/DE[e] + sum_local s_loc[p] ) ----------
__global__ void k_gather(const float* __restrict__ s_knn, const float* __restrict__ s_loc,
                         const int* __restrict__ inds, const int* __restrict__ DE,
                         float* __restrict__ z) {
  int c = threadIdx.x & 63;
  int u = blockIdx.x * 4 + (threadIdx.x >> 6);
  int ub = __builtin_amdgcn_readfirstlane(u);
  const int* ip = inds + (size_t)ub * KP1;
  float acc = 0.f;
  #pragma unroll
  for (int j = 0; j < KP1; ++j) {
    int e = ip[j];
    float invde = 1.0f / (float)DE[e];
    acc += s_knn[(size_t)e * CH + c] * invde;
  }
  int node = ub & 1023, b = ub >> 10;
  int rr = node >> 5, cc = node & 31;
  int i0 = rr - 4; if (i0 < 0) i0 = 0; i0 += (i0 & 1);
  int i1 = rr; if (i1 > 26) i1 = 26;
  int j0 = cc - 4; if (j0 < 0) j0 = 0; j0 += (j0 & 1);
  int j1 = cc; if (j1 > 26) j1 = 26;
  for (int i = i0; i <= i1; i += 2)
    for (int jj = j0; jj <= j1; jj += 2) {
      int e = b * 196 + (i >> 1) * 14 + (jj >> 1);
      acc += s_loc[(size_t)e * CH + c];
    }
  z[(size_t)ub * CH + c] = acc * dv2_of(ub);
}

// ---------- K6a: per-64-row-block partial BN sums ----------
__global__ void k_bnpart(const float* __restrict__ z, float* __restrict__ part,
                         float* __restrict__ partsq) {
  int c = threadIdx.x & 63;
  int rq = threadIdx.x >> 6;
  int blk = blockIdx.x;
  float s = 0.f, s2 = 0.f;
  for (int k = 0; k < 16; ++k) {
    float v = z[(size_t)(blk * 64 + rq * 16 + k) * CH + c];
    s += v; s2 += v * v;
  }
  __shared__ float ls[4][CH], ls2[4][CH];
  ls[rq][c] = s; ls2[rq][c] = s2;
  __syncthreads();
  if (rq == 0) {
    part[(size_t)blk * CH + c]   = ls[0][c] + ls[1][c] + ls[2][c] + ls[3][c];
    partsq[(size_t)blk * CH + c] = ls2[0][c] + ls2[1][c] + ls2[2][c] + ls2[3][c];
  }
}

// ---------- K6b: finalize mu / rstd ----------
__global__ void k_bnfin(const float* __restrict__ part, const float* __restrict__ partsq,
                        float* __restrict__ mu, float* __restrict__ rstd) {
  int c = threadIdx.x;
  float s = 0.f, s2 = 0.f;
  for (int b = 0; b < 128; ++b) { s += part[(size_t)b * CH + c]; s2 += partsq[(size_t)b * CH + c]; }
  float m = s * (1.0f / (float)BNTOT);
  float var = s2 * (1.0f / (float)BNTOT) - m * m;
  mu[c] = m;
  rstd[c] = 1.0f / sqrtf(var + 1e-5f);
}

// ---------- K7: BN apply + relu + residual ----------
__global__ void k_out(const float* __restrict__ z, const float* __restrict__ X,
                      const float* __restrict__ mu, const float* __restrict__ rstd,
                      const float* __restrict__ gamma, const float* __restrict__ beta,
                      float* __restrict__ out) {
  int c = threadIdx.x & 63;
  int u = blockIdx.x * 4 + (threadIdx.x >> 6);
  size_t idx = (size_t)u * CH + c;
  float zn = (z[idx] - mu[c]) * rstd[c] * gamma[c] + beta[c];
  out[idx] = fmaxf(zn, 0.f) + X[idx];
}

// ---------- launch ----------
extern "C" void kernel_launch(void* const* d_in, const int* in_sizes, int n_in,
                              void* d_out, int out_size, void* d_ws, size_t ws_size,
                              hipStream_t stream) {
  const float* X     = (const float*)d_in[0];
  const float* W     = (const float*)d_in[1];
  const float* bias  = (const float*)d_in[2];
  const float* gamma = (const float*)d_in[3];
  const float* beta  = (const float*)d_in[4];
  float* out = (float*)d_out;

  // workspace layout
  float* ws = (float*)d_ws;
  float* sq      = ws;                       // 8192
  float* thr     = sq + 8192;                // 8192
  float* t       = thr + 8192;               // 524288
  float* s_loc   = t + 524288;               // 100352
  float* z       = s_loc + 100352;           // 524288
  float* part    = z + 524288;               // 8192
  float* partsq  = part + 8192;              // 8192
  float* mu      = partsq + 8192;            // 64
  float* rstd    = mu + 64;                  // 64
  float* thrpart = rstd + 64;                // 1024*64*11 = 720896
  int*   inds    = (int*)(thrpart + 720896); // 90112 ints
  unsigned short* Xh = (unsigned short*)(inds + 90112);   // 524288 shorts
  uint2* cand    = (uint2*)(Xh + 524288);                 // 8192*256 uint2 = 16 MB
  // zeroed region: cnt (8192 int) + DE (8192 int) + s_knn (524288 f), contiguous
  int*   cnt    = (int*)(cand + (size_t)8192 * CAP);
  int*   DE     = cnt + 8192;
  float* s_knn  = (float*)(DE + 8192);

  hipMemsetAsync(cnt, 0, (size_t)(8192 + 8192 + 524288) * 4, stream);

  k_cast    <<<2048, 256, 0, stream>>>(X, Xh, sq);
  k_thrpart <<<1024, 256, 0, stream>>>(X, sq, thrpart);
  k_thrmerge<<<128, 64, 0, stream>>>(thrpart, thr);
  k_filter  <<<4096, 256, 0, stream>>>(Xh, sq, thr, cnt, cand);
  k_rescore <<<2048, 256, 0, stream>>>(X, sq, cnt, cand, inds, DE);
  k_lin     <<<512, 256, 0, stream>>>(X, W, bias, t);
  k_scatter <<<BNTOT / 4, 256, 0, stream>>>(t, inds, s_knn);
  k_local   <<<NLOC / 4, 256, 0, stream>>>(t, s_loc);
  k_gather  <<<BNTOT / 4, 256, 0, stream>>>(s_knn, s_loc, inds, DE, z);
  k_bnpart  <<<128, 256, 0, stream>>>(z, part, partsq);
  k_bnfin   <<<1, 64, 0, stream>>>(part, partsq, mu, rstd);
  k_out     <<<BNTOT / 4, 256, 0, stream>>>(z, X, mu, rstd, gamma, beta, out);

  (void)in_sizes; (void)n_in; (void)out_size; (void)ws_size;
}